// Round 1
// baseline (2134.685 us; speedup 1.0000x reference)
//
#include <hip/hip_runtime.h>
#include <hip/hip_bf16.h>
#include <math.h>

#define N_NODES 10000
#define N_EDGES 320000
#define HEADS   4
#define CDIM    128
#define HC      512   // HEADS*CDIM
#define LAYERS  4
#define DIN     7
#define EDIM    5

__device__ __forceinline__ void atomAddF(float* p, float v) { unsafeAtomicAdd(p, v); }

// ---------------- embed: h = relu(x @ embW + embB) ----------------
__global__ __launch_bounds__(256) void embed_kernel(
    const float* __restrict__ x, const float* __restrict__ W,
    const float* __restrict__ b, float* __restrict__ h)
{
  int t = blockIdx.x * 256 + threadIdx.x;            // N*128 threads
  int n = t >> 7, c = t & 127;
  float acc = b[c];
#pragma unroll
  for (int k = 0; k < DIN; ++k) acc += x[n * DIN + k] * W[k * CDIM + c];
  h[t] = fmaxf(acc, 0.f);
}

// ---------------- degree histogram ----------------
__global__ __launch_bounds__(256) void hist_kernel(
    const int* __restrict__ ei, int* __restrict__ degD, int* __restrict__ degS)
{
  int e = blockIdx.x * 256 + threadIdx.x;
  if (e < N_EDGES) {
    atomicAdd(&degS[ei[e]], 1);
    atomicAdd(&degD[ei[N_EDGES + e]], 1);
  }
}

// ---------------- exclusive scan (single block, 1024 thr = 16 waves) ----------------
__global__ __launch_bounds__(1024) void scan_kernel(
    const int* __restrict__ degD, int* __restrict__ offD, int* __restrict__ curD,
    const int* __restrict__ degS, int* __restrict__ offS, int* __restrict__ curS, int n)
{
  __shared__ int wsum[16];
  __shared__ int carry;
  int tid = threadIdx.x, wid = tid >> 6, lane = tid & 63;
  for (int arr = 0; arr < 2; ++arr) {
    const int* deg = arr ? degS : degD;
    int* off = arr ? offS : offD;
    int* cur = arr ? curS : curD;
    if (tid == 0) carry = 0;
    __syncthreads();
    for (int base = 0; base < n; base += 1024) {
      int i = base + tid;
      int v = (i < n) ? deg[i] : 0;
      int incl = v;
#pragma unroll
      for (int o = 1; o < 64; o <<= 1) {
        int t2 = __shfl_up(incl, o);
        if (lane >= o) incl += t2;
      }
      if (lane == 63) wsum[wid] = incl;
      __syncthreads();
      if (tid < 16) {
        int wv = wsum[tid];
#pragma unroll
        for (int o = 1; o < 16; o <<= 1) {
          int t2 = __shfl_up(wv, o);
          if (tid >= o) wv += t2;
        }
        wsum[tid] = wv;
      }
      __syncthreads();
      int woff = (wid > 0) ? wsum[wid - 1] : 0;
      int excl = carry + woff + incl - v;
      if (i < n) { off[i] = excl; cur[i] = excl; }
      __syncthreads();
      if (tid == 0) carry += wsum[15];
      __syncthreads();
    }
    if (tid == 0) off[n] = carry;
    __syncthreads();
  }
}

// ---------------- CSR scatter ----------------
__global__ __launch_bounds__(256) void scatter_kernel(
    const int* __restrict__ ei, int* __restrict__ curD, int* __restrict__ curS,
    int* __restrict__ eidD, int* __restrict__ eidS)
{
  int e = blockIdx.x * 256 + threadIdx.x;
  if (e < N_EDGES) {
    int s = ei[e], d = ei[N_EDGES + e];
    int p = atomicAdd(&curD[d], 1);
    eidD[p] = e;
    int q = atomicAdd(&curS[s], 1);
    eidS[q] = e;
  }
}

// ---------------- fp32 tiled GEMM: C[M,Nn] = A[M,K] @ B[K,Nn] ----------------
// BM=BN=128, BK=16, 256 threads, 8x8 micro-tile. Nn,K multiples of 16/128; M guarded.
__global__ __launch_bounds__(256) void gemm_kernel(
    const float* __restrict__ A, const float* __restrict__ B, float* __restrict__ C,
    int M, int K, int lda, int ldb, int ldc)
{
  __shared__ __align__(16) float sA[16][132];   // [k][m]
  __shared__ __align__(16) float sB[16][132];   // [k][n]
  int bm = blockIdx.y * 128, bn = blockIdx.x * 128;
  int tid = threadIdx.x;
  int tx = tid & 15, ty = tid >> 4;
  float acc[8][8];
#pragma unroll
  for (int i = 0; i < 8; ++i)
#pragma unroll
    for (int j = 0; j < 8; ++j) acc[i][j] = 0.f;

  for (int k0 = 0; k0 < K; k0 += 16) {
#pragma unroll
    for (int i = 0; i < 8; ++i) {
      int flat = tid + i * 256;        // 2048 = 128x16
      int m = flat >> 4, k = flat & 15;
      float v = 0.f;
      if (bm + m < M) v = A[(size_t)(bm + m) * lda + k0 + k];
      sA[k][m] = v;
    }
#pragma unroll
    for (int i = 0; i < 8; ++i) {
      int flat = tid + i * 256;        // 2048 = 16x128
      int k = flat >> 7, nn = flat & 127;
      sB[k][nn] = B[(size_t)(k0 + k) * ldb + bn + nn];
    }
    __syncthreads();
#pragma unroll
    for (int k = 0; k < 16; ++k) {
      float4 a0 = *(const float4*)&sA[k][ty * 8];
      float4 a1 = *(const float4*)&sA[k][ty * 8 + 4];
      float4 b0 = *(const float4*)&sB[k][tx * 8];
      float4 b1 = *(const float4*)&sB[k][tx * 8 + 4];
      float av[8] = {a0.x, a0.y, a0.z, a0.w, a1.x, a1.y, a1.z, a1.w};
      float bv[8] = {b0.x, b0.y, b0.z, b0.w, b1.x, b1.y, b1.z, b1.w};
#pragma unroll
      for (int i = 0; i < 8; ++i)
#pragma unroll
        for (int j = 0; j < 8; ++j) acc[i][j] += av[i] * bv[j];
    }
    __syncthreads();
  }
#pragma unroll
  for (int i = 0; i < 8; ++i) {
    int m = bm + ty * 8 + i;
    if (m < M) {
      float4 o0 = make_float4(acc[i][0], acc[i][1], acc[i][2], acc[i][3]);
      float4 o1 = make_float4(acc[i][4], acc[i][5], acc[i][6], acc[i][7]);
      *(float4*)&C[(size_t)m * ldc + bn + tx * 8] = o0;
      *(float4*)&C[(size_t)m * ldc + bn + tx * 8 + 4] = o1;
    }
  }
}

// ---------------- GATv2: per-node online-softmax aggregation, fused relu+res+LN ----------------
// block = 256 thr = 4 waves; one block per dst node. lane owns 8 of the 512 (h,c) elems.
__global__ __launch_bounds__(256) void gat_agg_kernel(
    const float* __restrict__ h_in, float* __restrict__ h_out,
    const float* __restrict__ xl, const float* __restrict__ xr,
    const int* __restrict__ ei, const float* __restrict__ eattr,
    const int* __restrict__ offD, const int* __restrict__ eidD,
    const float* __restrict__ We, const float* __restrict__ att,
    const float* __restrict__ gbias, const float* __restrict__ lng,
    const float* __restrict__ lnb)
{
  __shared__ float sWe[EDIM * HC];
  __shared__ float sAtt[HC];
  __shared__ float sAcc[4][HC];
  __shared__ float sMw[4][4], sDw[4][4], sMh[4], sDh[4];
  __shared__ float sOut[HC];
  __shared__ float sRed[256], sRed2[256];

  int n = blockIdx.x;
  int tid = threadIdx.x;
  for (int i = tid; i < EDIM * HC; i += 256) sWe[i] = We[i];
  for (int i = tid; i < HC; i += 256) sAtt[i] = att[i];
  int w = tid >> 6, lane = tid & 63;
  int base = lane * 8;

  float xr_reg[8];
  {
    float4 x0 = *(const float4*)&xr[(size_t)n * HC + base];
    float4 x1 = *(const float4*)&xr[(size_t)n * HC + base + 4];
    xr_reg[0] = x0.x; xr_reg[1] = x0.y; xr_reg[2] = x0.z; xr_reg[3] = x0.w;
    xr_reg[4] = x1.x; xr_reg[5] = x1.y; xr_reg[6] = x1.z; xr_reg[7] = x1.w;
  }
  __syncthreads();

  float m = -INFINITY, dsum = 0.f;
  float acc[8] = {0.f, 0.f, 0.f, 0.f, 0.f, 0.f, 0.f, 0.f};
  int e0 = offD[n], e1 = offD[n + 1];
  for (int idx = e0 + w; idx < e1; idx += 4) {
    int e = eidD[idx];
    int s = ei[e];
    float ea0 = eattr[e * 5 + 0], ea1 = eattr[e * 5 + 1], ea2 = eattr[e * 5 + 2],
          ea3 = eattr[e * 5 + 3], ea4 = eattr[e * 5 + 4];
    float4 x0 = *(const float4*)&xl[(size_t)s * HC + base];
    float4 x1 = *(const float4*)&xl[(size_t)s * HC + base + 4];
    float xlv[8] = {x0.x, x0.y, x0.z, x0.w, x1.x, x1.y, x1.z, x1.w};
    float logit = 0.f;
#pragma unroll
    for (int j = 0; j < 8; ++j) {
      float v = xlv[j] + xr_reg[j]
              + ea0 * sWe[base + j] + ea1 * sWe[HC + base + j]
              + ea2 * sWe[2 * HC + base + j] + ea3 * sWe[3 * HC + base + j]
              + ea4 * sWe[4 * HC + base + j];
      v = (v > 0.f) ? v : 0.2f * v;      // leaky_relu 0.2
      logit += v * sAtt[base + j];
    }
    logit += __shfl_xor(logit, 1);
    logit += __shfl_xor(logit, 2);
    logit += __shfl_xor(logit, 4);
    logit += __shfl_xor(logit, 8);       // full dot over the head's 128 elems
    float nm = fmaxf(m, logit);
    float sc = expf(m - nm);
    float p = expf(logit - nm);
    dsum = dsum * sc + p;
#pragma unroll
    for (int j = 0; j < 8; ++j) acc[j] = acc[j] * sc + p * xlv[j];
    m = nm;
  }
#pragma unroll
  for (int j = 0; j < 8; ++j) sAcc[w][base + j] = acc[j];
  if ((lane & 15) == 0) { sMw[w][lane >> 4] = m; sDw[w][lane >> 4] = dsum; }
  __syncthreads();

  if (tid < 4) {
    float M = fmaxf(fmaxf(sMw[0][tid], sMw[1][tid]), fmaxf(sMw[2][tid], sMw[3][tid]));
    float D = 0.f;
    if (M != -INFINITY) {
#pragma unroll
      for (int ww = 0; ww < 4; ++ww) D += sDw[ww][tid] * expf(sMw[ww][tid] - M);
    }
    sMh[tid] = M; sDh[tid] = D;
  }
  __syncthreads();

#pragma unroll
  for (int rr = 0; rr < 2; ++rr) {
    int hc = tid + rr * 256;
    int hh = hc >> 7;
    float M = sMh[hh], D = sDh[hh];
    float v = 0.f;
    if (D > 0.f) {
#pragma unroll
      for (int ww = 0; ww < 4; ++ww) v += sAcc[ww][hc] * expf(sMw[ww][hh] - M);
      v /= D;
    }
    sOut[hc] = v;
  }
  __syncthreads();

  float o = 0.f;
  if (tid < 128) {
    o = 0.25f * (sOut[tid] + sOut[128 + tid] + sOut[256 + tid] + sOut[384 + tid]) + gbias[tid];
    o = fmaxf(o, 0.f);                   // relu BEFORE residual
    o += h_in[(size_t)n * 128 + tid];
  }
  sRed[tid] = (tid < 128) ? o : 0.f;
  sRed2[tid] = (tid < 128) ? o * o : 0.f;
  __syncthreads();
  for (int st = 128; st >= 1; st >>= 1) {
    if (tid < st) { sRed[tid] += sRed[tid + st]; sRed2[tid] += sRed2[tid + st]; }
    __syncthreads();
  }
  if (tid < 128) {
    float mean = sRed[0] * (1.f / 128.f);
    float var = sRed2[0] * (1.f / 128.f) - mean * mean;
    float r = (o - mean) * rsqrtf(var + 1e-5f);
    h_out[(size_t)n * 128 + tid] = r * lng[tid] + lnb[tid];
  }
}

// ---------------- social pool edge kernel ----------------
// 64 src-sorted edges per block. t = relu(a[src]+b[dst]+b1); inter = t@W2+b2;
// gated = inter*sigmoid(inter@gW+gb); segmented atomic scatter by src.
__global__ __launch_bounds__(256) void sp_edge_kernel(
    const float* __restrict__ sa, const float* __restrict__ sb,
    const float* __restrict__ b1, const float* __restrict__ W2,
    const float* __restrict__ b2, const float* __restrict__ gW,
    const float* __restrict__ gb, const int* __restrict__ ei,
    const int* __restrict__ eidS, float* __restrict__ pool)
{
  __shared__ __align__(16) float sT[128][68];   // transposed tile: [col][row]
  __shared__ __align__(16) float sW[32][132];
  __shared__ int rsrc[64];
  __shared__ int rdst[64];
  int tid = threadIdx.x;
  int ebase = blockIdx.x * 64;
  if (tid < 64) {
    int idx = ebase + tid;
    int s = -1, d = 0;
    if (idx < N_EDGES) { int e = eidS[idx]; s = ei[e]; d = ei[N_EDGES + e]; }
    rsrc[tid] = s; rdst[tid] = d;
  }
  __syncthreads();

  // build t tile (coalesced global reads, transposed LDS store)
#pragma unroll
  for (int i = 0; i < 32; ++i) {
    int flat = tid + i * 256;          // 8192 = 64x128
    int r = flat >> 7, c = flat & 127;
    int s = rsrc[r];
    float v = 0.f;
    if (s >= 0) v = fmaxf(sa[s * 128 + c] + sb[rdst[r] * 128 + c] + b1[c], 0.f);
    sT[c][r] = v;
  }
  __syncthreads();

  int tx = tid & 31, ty = tid >> 5;    // cols c0 = tx*4 (of 128), rows r0 = ty*8 (of 64)
  int c0 = tx * 4, r0 = ty * 8;
  float acc1[8][4], acc2[8][4];
#pragma unroll
  for (int i = 0; i < 8; ++i)
#pragma unroll
    for (int j = 0; j < 4; ++j) { acc1[i][j] = 0.f; acc2[i][j] = 0.f; }

  // GEMM1: inter = t @ W2
  for (int k0 = 0; k0 < 128; k0 += 32) {
#pragma unroll
    for (int i = 0; i < 16; ++i) {
      int flat = tid + i * 256;        // 4096 = 32x128
      int k = flat >> 7, c = flat & 127;
      sW[k][c] = W2[(k0 + k) * 128 + c];
    }
    __syncthreads();
#pragma unroll
    for (int k = 0; k < 32; ++k) {
      float4 a0 = *(const float4*)&sT[k0 + k][r0];
      float4 a1 = *(const float4*)&sT[k0 + k][r0 + 4];
      float4 b0 = *(const float4*)&sW[k][c0];
      float av[8] = {a0.x, a0.y, a0.z, a0.w, a1.x, a1.y, a1.z, a1.w};
      float bv[4] = {b0.x, b0.y, b0.z, b0.w};
#pragma unroll
      for (int i = 0; i < 8; ++i)
#pragma unroll
        for (int j = 0; j < 4; ++j) acc1[i][j] += av[i] * bv[j];
    }
    __syncthreads();
  }
  // inter = acc1 + b2 ; write inter^T back into sT
#pragma unroll
  for (int j = 0; j < 4; ++j) {
    float bj = b2[c0 + j];
#pragma unroll
    for (int i = 0; i < 8; ++i) acc1[i][j] += bj;
    float4 w0 = make_float4(acc1[0][j], acc1[1][j], acc1[2][j], acc1[3][j]);
    float4 w1 = make_float4(acc1[4][j], acc1[5][j], acc1[6][j], acc1[7][j]);
    *(float4*)&sT[c0 + j][r0] = w0;
    *(float4*)&sT[c0 + j][r0 + 4] = w1;
  }
  __syncthreads();

  // GEMM2: g = inter @ gW
  for (int k0 = 0; k0 < 128; k0 += 32) {
#pragma unroll
    for (int i = 0; i < 16; ++i) {
      int flat = tid + i * 256;
      int k = flat >> 7, c = flat & 127;
      sW[k][c] = gW[(k0 + k) * 128 + c];
    }
    __syncthreads();
#pragma unroll
    for (int k = 0; k < 32; ++k) {
      float4 a0 = *(const float4*)&sT[k0 + k][r0];
      float4 a1 = *(const float4*)&sT[k0 + k][r0 + 4];
      float4 b0 = *(const float4*)&sW[k][c0];
      float av[8] = {a0.x, a0.y, a0.z, a0.w, a1.x, a1.y, a1.z, a1.w};
      float bv[4] = {b0.x, b0.y, b0.z, b0.w};
#pragma unroll
      for (int i = 0; i < 8; ++i)
#pragma unroll
        for (int j = 0; j < 4; ++j) acc2[i][j] += av[i] * bv[j];
    }
    __syncthreads();
  }
  // gated = inter * sigmoid(g + gb) ; store gated^T into sT
#pragma unroll
  for (int j = 0; j < 4; ++j) {
    float gbj = gb[c0 + j];
#pragma unroll
    for (int i = 0; i < 8; ++i) {
      float g = acc2[i][j] + gbj;
      float gate = 1.f / (1.f + expf(-g));
      acc1[i][j] = acc1[i][j] * gate;
    }
    float4 w0 = make_float4(acc1[0][j], acc1[1][j], acc1[2][j], acc1[3][j]);
    float4 w1 = make_float4(acc1[4][j], acc1[5][j], acc1[6][j], acc1[7][j]);
    *(float4*)&sT[c0 + j][r0] = w0;
    *(float4*)&sT[c0 + j][r0 + 4] = w1;
  }
  __syncthreads();

  // segmented scatter by src (rows are src-sorted)
  {
    int c = tid & 127, half = tid >> 7;
    int rbeg = half * 32, rend = rbeg + 32;
    int curs = -1; float run = 0.f;
    for (int r = rbeg; r < rend; ++r) {
      int s = rsrc[r];
      if (s != curs) {
        if (curs >= 0) atomAddF(&pool[curs * 128 + c], run);
        curs = s; run = 0.f;
      }
      if (s >= 0) run += sT[c][r];
    }
    if (curs >= 0) atomAddF(&pool[curs * 128 + c], run);
  }
}

// ---------------- finalize: out = LN(h + pool/max(cnt,1)) ----------------
// one wave per node, lane owns cols {lane, lane+64}
__global__ __launch_bounds__(256) void finalize_kernel(
    const float* __restrict__ h, const float* __restrict__ pool,
    const int* __restrict__ degS, const float* __restrict__ g,
    const float* __restrict__ b, float* __restrict__ out)
{
  int t = blockIdx.x * 256 + threadIdx.x;
  int n = t >> 6, lane = t & 63;
  if (n >= N_NODES) return;
  float cnt = fmaxf((float)degS[n], 1.f);
  float a = h[(size_t)n * 128 + lane] + pool[(size_t)n * 128 + lane] / cnt;
  float c2 = h[(size_t)n * 128 + 64 + lane] + pool[(size_t)n * 128 + 64 + lane] / cnt;
  float s = a + c2, s2 = a * a + c2 * c2;
#pragma unroll
  for (int o = 1; o < 64; o <<= 1) { s += __shfl_xor(s, o); s2 += __shfl_xor(s2, o); }
  float mean = s * (1.f / 128.f);
  float var = s2 * (1.f / 128.f) - mean * mean;
  float rs = rsqrtf(var + 1e-5f);
  out[(size_t)n * 128 + lane] = (a - mean) * rs * g[lane] + b[lane];
  out[(size_t)n * 128 + 64 + lane] = (c2 - mean) * rs * g[64 + lane] + b[64 + lane];
}

// ---------------- host ----------------
extern "C" void kernel_launch(void* const* d_in, const int* in_sizes, int n_in,
                              void* d_out, int out_size, void* d_ws, size_t ws_size,
                              hipStream_t stream) {
  (void)in_sizes; (void)n_in; (void)out_size; (void)ws_size;
  const float* x     = (const float*)d_in[0];
  const int*   ei    = (const int*)d_in[1];
  const float* eattr = (const float*)d_in[2];
  const float* embW  = (const float*)d_in[3];
  const float* embB  = (const float*)d_in[4];
  const float* gWl   = (const float*)d_in[5];
  const float* gWr   = (const float*)d_in[6];
  const float* gWe   = (const float*)d_in[7];
  const float* gAtt  = (const float*)d_in[8];
  const float* gB    = (const float*)d_in[9];
  const float* lnG   = (const float*)d_in[10];
  const float* lnB   = (const float*)d_in[11];
  const float* spW1  = (const float*)d_in[12];
  const float* spB1  = (const float*)d_in[13];
  const float* spW2  = (const float*)d_in[14];
  const float* spB2  = (const float*)d_in[15];
  const float* spGW  = (const float*)d_in[16];
  const float* spGB  = (const float*)d_in[17];
  const float* fnG   = (const float*)d_in[18];
  const float* fnB   = (const float*)d_in[19];
  float* out = (float*)d_out;

  char* ws = (char*)d_ws;
  size_t off = 0;
  auto alloc = [&](size_t bytes) {
    void* p = ws + off;
    off = (off + bytes + 255) & ~(size_t)255;
    return p;
  };
  float* hA   = (float*)alloc((size_t)N_NODES * 128 * 4);
  float* hB   = (float*)alloc((size_t)N_NODES * 128 * 4);
  float* xl   = (float*)alloc((size_t)N_NODES * 512 * 4);
  float* xr   = (float*)alloc((size_t)N_NODES * 512 * 4);
  float* saP  = (float*)alloc((size_t)N_NODES * 128 * 4);
  float* sbP  = (float*)alloc((size_t)N_NODES * 128 * 4);
  float* pool = (float*)alloc((size_t)N_NODES * 128 * 4);
  int* degD = (int*)alloc((size_t)N_NODES * 4);
  int* degS = (int*)alloc((size_t)N_NODES * 4);
  int* offD = (int*)alloc((size_t)(N_NODES + 1) * 4);
  int* offS = (int*)alloc((size_t)(N_NODES + 1) * 4);
  int* curD = (int*)alloc((size_t)N_NODES * 4);
  int* curS = (int*)alloc((size_t)N_NODES * 4);
  int* eidD = (int*)alloc((size_t)N_EDGES * 4);
  int* eidS = (int*)alloc((size_t)N_EDGES * 4);

  hipMemsetAsync(degD, 0, (size_t)N_NODES * 4, stream);
  hipMemsetAsync(degS, 0, (size_t)N_NODES * 4, stream);
  hipMemsetAsync(pool, 0, (size_t)N_NODES * 128 * 4, stream);

  embed_kernel<<<(N_NODES * 128) / 256, 256, 0, stream>>>(x, embW, embB, hA);
  hist_kernel<<<(N_EDGES + 255) / 256, 256, 0, stream>>>(ei, degD, degS);
  scan_kernel<<<1, 1024, 0, stream>>>(degD, offD, curD, degS, offS, curS, N_NODES);
  scatter_kernel<<<(N_EDGES + 255) / 256, 256, 0, stream>>>(ei, curD, curS, eidD, eidS);

  const int MB = (N_NODES + 127) / 128;   // 79
  float* hcur = hA;
  float* hnext = hB;
  for (int l = 0; l < LAYERS; ++l) {
    gemm_kernel<<<dim3(4, MB), 256, 0, stream>>>(hcur, gWl + (size_t)l * 128 * 512, xl,
                                                 N_NODES, 128, 128, 512, 512);
    gemm_kernel<<<dim3(4, MB), 256, 0, stream>>>(hcur, gWr + (size_t)l * 128 * 512, xr,
                                                 N_NODES, 128, 128, 512, 512);
    gat_agg_kernel<<<N_NODES, 256, 0, stream>>>(hcur, hnext, xl, xr, ei, eattr, offD, eidD,
                                                gWe + (size_t)l * EDIM * HC,
                                                gAtt + (size_t)l * HC,
                                                gB + (size_t)l * 128,
                                                lnG + (size_t)l * 128,
                                                lnB + (size_t)l * 128);
    float* tmp = hcur; hcur = hnext; hnext = tmp;
  }
  // hcur == hA after 4 layers
  gemm_kernel<<<dim3(1, MB), 256, 0, stream>>>(hcur, spW1, saP, N_NODES, 128, 128, 128, 128);
  gemm_kernel<<<dim3(1, MB), 256, 0, stream>>>(hcur, spW1 + 128 * 128, sbP, N_NODES, 128, 128, 128, 128);
  sp_edge_kernel<<<(N_EDGES + 63) / 64, 256, 0, stream>>>(saP, sbP, spB1, spW2, spB2, spGW,
                                                          spGB, ei, eidS, pool);
  finalize_kernel<<<(N_NODES + 3) / 4, 256, 0, stream>>>(hcur, pool, degS, fnG, fnB, out);
}

// Round 2
// 1044.971 us; speedup vs baseline: 2.0428x; 2.0428x over previous
//
#include <hip/hip_runtime.h>
#include <hip/hip_bf16.h>
#include <math.h>

#define N_NODES 10000
#define N_EDGES 320000
#define HEADS   4
#define CDIM    128
#define HC      512
#define LAYERS  4
#define DIN     7
#define EDIM    5

typedef short short8 __attribute__((ext_vector_type(8)));
typedef unsigned short us8 __attribute__((ext_vector_type(8)));
typedef float f32x4 __attribute__((ext_vector_type(4)));

__device__ __forceinline__ void atomAddF(float* p, float v) { unsafeAtomicAdd(p, v); }

__device__ __forceinline__ unsigned short f2bf(float f) {
  unsigned u = __float_as_uint(f);
  unsigned r = u + 0x7fffu + ((u >> 16) & 1u);
  return (unsigned short)(r >> 16);
}
__device__ __forceinline__ float bf2f(unsigned short u) {
  return __uint_as_float(((unsigned)u) << 16);
}

// ---------------- embed: h = relu(x @ embW + embB), fp32 + bf16 copies ----------------
__global__ __launch_bounds__(256) void embed_kernel(
    const float* __restrict__ x, const float* __restrict__ W,
    const float* __restrict__ b, float* __restrict__ h, unsigned short* __restrict__ hbf)
{
  int t = blockIdx.x * 256 + threadIdx.x;
  int n = t >> 7, c = t & 127;
  float acc = b[c];
#pragma unroll
  for (int k = 0; k < DIN; ++k) acc += x[n * DIN + k] * W[k * CDIM + c];
  acc = fmaxf(acc, 0.f);
  h[t] = acc;
  hbf[t] = f2bf(acc);
}

// ---------------- weight pack: bf16 + transpose ----------------
// WlrT[l][n][k] (n<512 -> Wl, else Wr); W1T[n][k]; W2T[n][k]; gWT[n][k]
__global__ __launch_bounds__(256) void pack_kernel(
    const float* __restrict__ Wl, const float* __restrict__ Wr,
    const float* __restrict__ W1, const float* __restrict__ W2,
    const float* __restrict__ gW, unsigned short* __restrict__ WlrT,
    unsigned short* __restrict__ W1T, unsigned short* __restrict__ W2T,
    unsigned short* __restrict__ gWT)
{
  int t = blockIdx.x * 256 + threadIdx.x;
  if (t < 524288) {                       // 4*1024*128
    int k = t & 127, n = (t >> 7) & 1023, l = t >> 17;
    float v = (n < 512) ? Wl[(size_t)(l * 128 + k) * 512 + n]
                        : Wr[(size_t)(l * 128 + k) * 512 + (n - 512)];
    WlrT[t] = f2bf(v);
  } else if (t < 524288 + 32768) {        // 256*128
    int u = t - 524288; int k = u & 127, n = u >> 7;
    float v = (n < 128) ? W1[k * 128 + n] : W1[(128 + k) * 128 + (n - 128)];
    W1T[u] = f2bf(v);
  } else if (t < 557056 + 16384) {
    int u = t - 557056; int k = u & 127, n = u >> 7;
    W2T[u] = f2bf(W2[k * 128 + n]);
  } else if (t < 573440 + 16384) {
    int u = t - 573440; int k = u & 127, n = u >> 7;
    gWT[u] = f2bf(gW[k * 128 + n]);
  }
}

// ---------------- degree histogram ----------------
__global__ __launch_bounds__(256) void hist_kernel(
    const int* __restrict__ ei, int* __restrict__ degD, int* __restrict__ degS)
{
  int e = blockIdx.x * 256 + threadIdx.x;
  if (e < N_EDGES) {
    atomicAdd(&degS[ei[e]], 1);
    atomicAdd(&degD[ei[N_EDGES + e]], 1);
  }
}

// ---------------- exclusive scan ----------------
__global__ __launch_bounds__(1024) void scan_kernel(
    const int* __restrict__ degD, int* __restrict__ offD, int* __restrict__ curD,
    const int* __restrict__ degS, int* __restrict__ offS, int* __restrict__ curS, int n)
{
  __shared__ int wsum[16];
  __shared__ int carry;
  int tid = threadIdx.x, wid = tid >> 6, lane = tid & 63;
  for (int arr = 0; arr < 2; ++arr) {
    const int* deg = arr ? degS : degD;
    int* off = arr ? offS : offD;
    int* cur = arr ? curS : curD;
    if (tid == 0) carry = 0;
    __syncthreads();
    for (int base = 0; base < n; base += 1024) {
      int i = base + tid;
      int v = (i < n) ? deg[i] : 0;
      int incl = v;
#pragma unroll
      for (int o = 1; o < 64; o <<= 1) {
        int t2 = __shfl_up(incl, o);
        if (lane >= o) incl += t2;
      }
      if (lane == 63) wsum[wid] = incl;
      __syncthreads();
      if (tid < 16) {
        int wv = wsum[tid];
#pragma unroll
        for (int o = 1; o < 16; o <<= 1) {
          int t2 = __shfl_up(wv, o);
          if (tid >= o) wv += t2;
        }
        wsum[tid] = wv;
      }
      __syncthreads();
      int woff = (wid > 0) ? wsum[wid - 1] : 0;
      int excl = carry + woff + incl - v;
      if (i < n) { off[i] = excl; cur[i] = excl; }
      __syncthreads();
      if (tid == 0) carry += wsum[15];
      __syncthreads();
    }
    if (tid == 0) off[n] = carry;
    __syncthreads();
  }
}

// ---------------- CSR scatter ----------------
__global__ __launch_bounds__(256) void scatter_kernel(
    const int* __restrict__ ei, int* __restrict__ curD, int* __restrict__ curS,
    int* __restrict__ eidD, int* __restrict__ eidS)
{
  int e = blockIdx.x * 256 + threadIdx.x;
  if (e < N_EDGES) {
    int s = ei[e], d = ei[N_EDGES + e];
    int p = atomicAdd(&curD[d], 1);
    eidD[p] = e;
    int q = atomicAdd(&curS[s], 1);
    eidS[q] = e;
  }
}

// ---------------- bf16 MFMA GEMM: C[M,N](bf16) = A[M,128](bf16) @ BT[N,128](bf16)^T ----
// BM=BN=64, K=128 single shot. 256 thr = 4 waves (2x2). XOR chunk-swizzled LDS.
__global__ __launch_bounds__(256) void mfma_gemm_kernel(
    const unsigned short* __restrict__ A, const unsigned short* __restrict__ BT,
    unsigned short* __restrict__ C, int M, int ldc)
{
  __shared__ __align__(16) unsigned short sA[64 * 128];
  __shared__ __align__(16) unsigned short sB[64 * 128];
  int tid = threadIdx.x;
  int bm = blockIdx.y * 64, bn = blockIdx.x * 64;
#pragma unroll
  for (int i = 0; i < 4; ++i) {
    int ch = tid + i * 256;            // 1024 chunks of 16B
    int r = ch >> 4, kc = ch & 15;
    int gr = bm + r;
    short8 v = {0, 0, 0, 0, 0, 0, 0, 0};
    if (gr < M) v = *(const short8*)&A[(size_t)gr * 128 + kc * 8];
    *(short8*)&sA[r * 128 + ((kc ^ (r & 7)) * 8)] = v;
  }
#pragma unroll
  for (int i = 0; i < 4; ++i) {
    int ch = tid + i * 256;
    int r = ch >> 4, kc = ch & 15;
    short8 v = *(const short8*)&BT[(size_t)(bn + r) * 128 + kc * 8];
    *(short8*)&sB[r * 128 + ((kc ^ (r & 7)) * 8)] = v;
  }
  __syncthreads();
  int w = tid >> 6, lane = tid & 63;
  int wr = (w >> 1) * 32, wc = (w & 1) * 32;
  int l15 = lane & 15, q = lane >> 4;
  f32x4 acc00 = {0, 0, 0, 0}, acc01 = acc00, acc10 = acc00, acc11 = acc00;
#pragma unroll
  for (int ks = 0; ks < 4; ++ks) {
    int c0 = ks * 4 + q;
    int m0 = wr + l15, m1 = m0 + 16;
    int n0 = wc + l15, n1 = n0 + 16;
    short8 a0 = *(const short8*)&sA[m0 * 128 + ((c0 ^ (m0 & 7)) * 8)];
    short8 a1 = *(const short8*)&sA[m1 * 128 + ((c0 ^ (m1 & 7)) * 8)];
    short8 b0 = *(const short8*)&sB[n0 * 128 + ((c0 ^ (n0 & 7)) * 8)];
    short8 b1 = *(const short8*)&sB[n1 * 128 + ((c0 ^ (n1 & 7)) * 8)];
    acc00 = __builtin_amdgcn_mfma_f32_16x16x32_bf16(a0, b0, acc00, 0, 0, 0);
    acc01 = __builtin_amdgcn_mfma_f32_16x16x32_bf16(a0, b1, acc01, 0, 0, 0);
    acc10 = __builtin_amdgcn_mfma_f32_16x16x32_bf16(a1, b0, acc10, 0, 0, 0);
    acc11 = __builtin_amdgcn_mfma_f32_16x16x32_bf16(a1, b1, acc11, 0, 0, 0);
  }
#pragma unroll
  for (int mf = 0; mf < 2; ++mf) {
#pragma unroll
    for (int nf = 0; nf < 2; ++nf) {
      f32x4 acc = mf == 0 ? (nf == 0 ? acc00 : acc01) : (nf == 0 ? acc10 : acc11);
      int col = bn + wc + nf * 16 + l15;
#pragma unroll
      for (int r = 0; r < 4; ++r) {
        int row = bm + wr + mf * 16 + 4 * q + r;
        if (row < M) C[(size_t)row * ldc + col] = f2bf(acc[r]);
      }
    }
  }
}

// ---------------- GATv2 aggregation (bf16 xl/xr gathers) + relu + residual + LN ------
__global__ __launch_bounds__(256) void gat_agg_kernel(
    const float* __restrict__ h_in, float* __restrict__ h_out,
    unsigned short* __restrict__ hbf_out, const unsigned short* __restrict__ xlr,
    const int* __restrict__ ei, const float* __restrict__ eattr,
    const int* __restrict__ offD, const int* __restrict__ eidD,
    const float* __restrict__ We, const float* __restrict__ att,
    const float* __restrict__ gbias, const float* __restrict__ lng,
    const float* __restrict__ lnb)
{
  __shared__ float sWe[EDIM * HC];
  __shared__ float sAtt[HC];
  __shared__ float sAcc[4][HC];
  __shared__ float sMw[4][4], sDw[4][4], sMh[4], sDh[4];
  __shared__ float sOut[HC];
  __shared__ float sRed[256], sRed2[256];

  int n = blockIdx.x;
  int tid = threadIdx.x;
  for (int i = tid; i < EDIM * HC; i += 256) sWe[i] = We[i];
  for (int i = tid; i < HC; i += 256) sAtt[i] = att[i];
  int w = tid >> 6, lane = tid & 63;
  int base = lane * 8;

  float xr_reg[8];
  {
    us8 u = *(const us8*)&xlr[(size_t)n * 1024 + 512 + base];
#pragma unroll
    for (int j = 0; j < 8; ++j) xr_reg[j] = bf2f(u[j]);
  }
  __syncthreads();

  float m = -INFINITY, dsum = 0.f;
  float acc[8] = {0.f, 0.f, 0.f, 0.f, 0.f, 0.f, 0.f, 0.f};
  int e0 = offD[n], e1 = offD[n + 1];
  for (int idx = e0 + w; idx < e1; idx += 4) {
    int e = eidD[idx];
    int s = ei[e];
    float ea0 = eattr[e * 5 + 0], ea1 = eattr[e * 5 + 1], ea2 = eattr[e * 5 + 2],
          ea3 = eattr[e * 5 + 3], ea4 = eattr[e * 5 + 4];
    us8 u = *(const us8*)&xlr[(size_t)s * 1024 + base];
    float xlv[8];
#pragma unroll
    for (int j = 0; j < 8; ++j) xlv[j] = bf2f(u[j]);
    float logit = 0.f;
#pragma unroll
    for (int j = 0; j < 8; ++j) {
      float v = xlv[j] + xr_reg[j]
              + ea0 * sWe[base + j] + ea1 * sWe[HC + base + j]
              + ea2 * sWe[2 * HC + base + j] + ea3 * sWe[3 * HC + base + j]
              + ea4 * sWe[4 * HC + base + j];
      v = (v > 0.f) ? v : 0.2f * v;
      logit += v * sAtt[base + j];
    }
    logit += __shfl_xor(logit, 1);
    logit += __shfl_xor(logit, 2);
    logit += __shfl_xor(logit, 4);
    logit += __shfl_xor(logit, 8);
    float nm = fmaxf(m, logit);
    float sc = expf(m - nm);
    float p = expf(logit - nm);
    dsum = dsum * sc + p;
#pragma unroll
    for (int j = 0; j < 8; ++j) acc[j] = acc[j] * sc + p * xlv[j];
    m = nm;
  }
#pragma unroll
  for (int j = 0; j < 8; ++j) sAcc[w][base + j] = acc[j];
  if ((lane & 15) == 0) { sMw[w][lane >> 4] = m; sDw[w][lane >> 4] = dsum; }
  __syncthreads();

  if (tid < 4) {
    float M = fmaxf(fmaxf(sMw[0][tid], sMw[1][tid]), fmaxf(sMw[2][tid], sMw[3][tid]));
    float D = 0.f;
    if (M != -INFINITY) {
#pragma unroll
      for (int ww = 0; ww < 4; ++ww) D += sDw[ww][tid] * expf(sMw[ww][tid] - M);
    }
    sMh[tid] = M; sDh[tid] = D;
  }
  __syncthreads();

#pragma unroll
  for (int rr = 0; rr < 2; ++rr) {
    int hc = tid + rr * 256;
    int hh = hc >> 7;
    float M = sMh[hh], D = sDh[hh];
    float v = 0.f;
    if (D > 0.f) {
#pragma unroll
      for (int ww = 0; ww < 4; ++ww) v += sAcc[ww][hc] * expf(sMw[ww][hh] - M);
      v /= D;
    }
    sOut[hc] = v;
  }
  __syncthreads();

  float o = 0.f;
  if (tid < 128) {
    o = 0.25f * (sOut[tid] + sOut[128 + tid] + sOut[256 + tid] + sOut[384 + tid]) + gbias[tid];
    o = fmaxf(o, 0.f);
    o += h_in[(size_t)n * 128 + tid];
  }
  sRed[tid] = (tid < 128) ? o : 0.f;
  sRed2[tid] = (tid < 128) ? o * o : 0.f;
  __syncthreads();
  for (int st = 128; st >= 1; st >>= 1) {
    if (tid < st) { sRed[tid] += sRed[tid + st]; sRed2[tid] += sRed2[tid + st]; }
    __syncthreads();
  }
  if (tid < 128) {
    float mean = sRed[0] * (1.f / 128.f);
    float var = sRed2[0] * (1.f / 128.f) - mean * mean;
    float r = (o - mean) * rsqrtf(var + 1e-5f);
    float val = r * lng[tid] + lnb[tid];
    h_out[(size_t)n * 128 + tid] = val;
    hbf_out[(size_t)n * 128 + tid] = f2bf(val);
  }
}

// ---------------- social pool edge kernel (bf16 MFMA) ----------------
// 64 src-sorted edges/block. T=relu(a[src]+b[dst]+b1) -> inter=T@W2+b2 ->
// gated=inter*sigmoid(inter@gW+gb) -> segmented scatter by src.
__global__ __launch_bounds__(256) void sp_edge_kernel(
    const unsigned short* __restrict__ sab, const float* __restrict__ b1,
    const unsigned short* __restrict__ W2T, const float* __restrict__ b2,
    const unsigned short* __restrict__ gWT, const float* __restrict__ gb,
    const int* __restrict__ ei, const int* __restrict__ eidS,
    float* __restrict__ pool)
{
  __shared__ __align__(16) unsigned short sT[64 * 128];   // 16KB A-operand (swizzled)
  __shared__ __align__(16) float sU[128 * 65];            // 33.3KB: B-operand / gatedT
  __shared__ int rsrc[64];
  __shared__ int rdst[64];
  unsigned short* sB = (unsigned short*)sU;               // 128x128 bf16 (swizzled)
  int tid = threadIdx.x;
  int ebase = blockIdx.x * 64;
  if (tid < 64) {
    int idx = ebase + tid;
    int s = -1, d = 0;
    if (idx < N_EDGES) { int e = eidS[idx]; s = ei[e]; d = ei[N_EDGES + e]; }
    rsrc[tid] = s; rdst[tid] = d;
  }
  __syncthreads();

  // build T tile: 1024 chunks of 8 cols
#pragma unroll
  for (int i = 0; i < 4; ++i) {
    int ch = tid + i * 256;
    int r = ch >> 4, kc = ch & 15, c0 = kc * 8;
    int s = rsrc[r];
    short8 o = {0, 0, 0, 0, 0, 0, 0, 0};
    if (s >= 0) {
      int d = rdst[r];
      us8 ua = *(const us8*)&sab[(size_t)s * 256 + c0];
      us8 ub = *(const us8*)&sab[(size_t)d * 256 + 128 + c0];
      float4 bb0 = *(const float4*)&b1[c0];
      float4 bb1 = *(const float4*)&b1[c0 + 4];
      float bv[8] = {bb0.x, bb0.y, bb0.z, bb0.w, bb1.x, bb1.y, bb1.z, bb1.w};
#pragma unroll
      for (int j = 0; j < 8; ++j)
        o[j] = (short)f2bf(fmaxf(bf2f(ua[j]) + bf2f(ub[j]) + bv[j], 0.f));
    }
    *(short8*)&sT[r * 128 + ((kc ^ (r & 7)) * 8)] = o;
  }
  // stage W2T
#pragma unroll
  for (int i = 0; i < 8; ++i) {
    int ch = tid + i * 256;            // 2048 chunks
    int n = ch >> 4, kc = ch & 15;
    short8 v = *(const short8*)&W2T[(size_t)n * 128 + kc * 8];
    *(short8*)&sB[n * 128 + ((kc ^ (n & 7)) * 8)] = v;
  }
  __syncthreads();

  int w = tid >> 6, lane = tid & 63;
  int r0 = w * 16;                     // 16 edge-rows per wave
  int l15 = lane & 15, q = lane >> 4;

  // GEMM1: inter = T @ W2 (+b2). acc1[nf] covers cols nf*16..+16
  f32x4 acc1[8], acc2[8];
#pragma unroll
  for (int i = 0; i < 8; ++i) { acc1[i] = (f32x4){0, 0, 0, 0}; acc2[i] = acc1[i]; }
  {
    short8 a[4];
#pragma unroll
    for (int ks = 0; ks < 4; ++ks) {
      int m = r0 + l15;
      a[ks] = *(const short8*)&sT[m * 128 + (((ks * 4 + q) ^ (m & 7)) * 8)];
    }
#pragma unroll
    for (int nf = 0; nf < 8; ++nf) {
      int n = nf * 16 + l15;
#pragma unroll
      for (int ks = 0; ks < 4; ++ks) {
        short8 b = *(const short8*)&sB[n * 128 + (((ks * 4 + q) ^ (n & 7)) * 8)];
        acc1[nf] = __builtin_amdgcn_mfma_f32_16x16x32_bf16(a[ks], b, acc1[nf], 0, 0, 0);
      }
    }
  }
#pragma unroll
  for (int nf = 0; nf < 8; ++nf) {
    float bias = b2[nf * 16 + l15];
#pragma unroll
    for (int r = 0; r < 4; ++r) acc1[nf][r] += bias;
  }
  __syncthreads();   // all GEMM1 LDS reads done

  // write inter(bf16) into sT (own-wave rows only) + stage gWT into sB
#pragma unroll
  for (int nf = 0; nf < 8; ++nf) {
    int colN = nf * 16 + l15;
    int kc = colN >> 3, j = colN & 7;
#pragma unroll
    for (int r = 0; r < 4; ++r) {
      int row = r0 + 4 * q + r;
      sT[row * 128 + ((kc ^ (row & 7)) * 8) + j] = f2bf(acc1[nf][r]);
    }
  }
#pragma unroll
  for (int i = 0; i < 8; ++i) {
    int ch = tid + i * 256;
    int n = ch >> 4, kc = ch & 15;
    short8 v = *(const short8*)&gWT[(size_t)n * 128 + kc * 8];
    *(short8*)&sB[n * 128 + ((kc ^ (n & 7)) * 8)] = v;
  }
  __syncthreads();

  // GEMM2: g = inter @ gW
  {
    short8 a[4];
#pragma unroll
    for (int ks = 0; ks < 4; ++ks) {
      int m = r0 + l15;
      a[ks] = *(const short8*)&sT[m * 128 + (((ks * 4 + q) ^ (m & 7)) * 8)];
    }
#pragma unroll
    for (int nf = 0; nf < 8; ++nf) {
      int n = nf * 16 + l15;
#pragma unroll
      for (int ks = 0; ks < 4; ++ks) {
        short8 b = *(const short8*)&sB[n * 128 + (((ks * 4 + q) ^ (n & 7)) * 8)];
        acc2[nf] = __builtin_amdgcn_mfma_f32_16x16x32_bf16(a[ks], b, acc2[nf], 0, 0, 0);
      }
    }
  }
  __syncthreads();   // all GEMM2 LDS reads done

  // gated = inter * sigmoid(g+gb); write gatedT fp32 at stride 65 (conflict-free)
  float* gT = sU;
#pragma unroll
  for (int nf = 0; nf < 8; ++nf) {
    int colN = nf * 16 + l15;
    float gbias = gb[colN];
#pragma unroll
    for (int r = 0; r < 4; ++r) {
      float g = acc2[nf][r] + gbias;
      float gate = 1.f / (1.f + expf(-g));
      int row = r0 + 4 * q + r;
      gT[colN * 65 + row] = acc1[nf][r] * gate;
    }
  }
  __syncthreads();

  // segmented scatter by src
  {
    int c = tid & 127, half = tid >> 7;
    int rbeg = half * 32, rend = rbeg + 32;
    int curs = -1; float run = 0.f;
    for (int r = rbeg; r < rend; ++r) {
      int s = rsrc[r];
      if (s != curs) {
        if (curs >= 0) atomAddF(&pool[(size_t)curs * 128 + c], run);
        curs = s; run = 0.f;
      }
      if (s >= 0) run += gT[c * 65 + r];
    }
    if (curs >= 0) atomAddF(&pool[(size_t)curs * 128 + c], run);
  }
}

// ---------------- finalize: out = LN(h + pool/max(cnt,1)) ----------------
__global__ __launch_bounds__(256) void finalize_kernel(
    const float* __restrict__ h, const float* __restrict__ pool,
    const int* __restrict__ degS, const float* __restrict__ g,
    const float* __restrict__ b, float* __restrict__ out)
{
  int t = blockIdx.x * 256 + threadIdx.x;
  int n = t >> 6, lane = t & 63;
  if (n >= N_NODES) return;
  float cnt = fmaxf((float)degS[n], 1.f);
  float a = h[(size_t)n * 128 + lane] + pool[(size_t)n * 128 + lane] / cnt;
  float c2 = h[(size_t)n * 128 + 64 + lane] + pool[(size_t)n * 128 + 64 + lane] / cnt;
  float s = a + c2, s2 = a * a + c2 * c2;
#pragma unroll
  for (int o = 1; o < 64; o <<= 1) { s += __shfl_xor(s, o); s2 += __shfl_xor(s2, o); }
  float mean = s * (1.f / 128.f);
  float var = s2 * (1.f / 128.f) - mean * mean;
  float rs = rsqrtf(var + 1e-5f);
  out[(size_t)n * 128 + lane] = (a - mean) * rs * g[lane] + b[lane];
  out[(size_t)n * 128 + 64 + lane] = (c2 - mean) * rs * g[64 + lane] + b[64 + lane];
}

// ---------------- host ----------------
extern "C" void kernel_launch(void* const* d_in, const int* in_sizes, int n_in,
                              void* d_out, int out_size, void* d_ws, size_t ws_size,
                              hipStream_t stream) {
  (void)in_sizes; (void)n_in; (void)out_size; (void)ws_size;
  const float* x     = (const float*)d_in[0];
  const int*   ei    = (const int*)d_in[1];
  const float* eattr = (const float*)d_in[2];
  const float* embW  = (const float*)d_in[3];
  const float* embB  = (const float*)d_in[4];
  const float* gWl   = (const float*)d_in[5];
  const float* gWr   = (const float*)d_in[6];
  const float* gWe   = (const float*)d_in[7];
  const float* gAtt  = (const float*)d_in[8];
  const float* gB    = (const float*)d_in[9];
  const float* lnG   = (const float*)d_in[10];
  const float* lnB   = (const float*)d_in[11];
  const float* spW1  = (const float*)d_in[12];
  const float* spB1  = (const float*)d_in[13];
  const float* spW2  = (const float*)d_in[14];
  const float* spB2  = (const float*)d_in[15];
  const float* spGW  = (const float*)d_in[16];
  const float* spGB  = (const float*)d_in[17];
  const float* fnG   = (const float*)d_in[18];
  const float* fnB   = (const float*)d_in[19];
  float* out = (float*)d_out;

  char* ws = (char*)d_ws;
  size_t off = 0;
  auto alloc = [&](size_t bytes) {
    void* p = ws + off;
    off = (off + bytes + 255) & ~(size_t)255;
    return p;
  };
  float* hA   = (float*)alloc((size_t)N_NODES * 128 * 4);
  float* hB   = (float*)alloc((size_t)N_NODES * 128 * 4);
  unsigned short* hbfA = (unsigned short*)alloc((size_t)N_NODES * 128 * 2);
  unsigned short* hbfB = (unsigned short*)alloc((size_t)N_NODES * 128 * 2);
  unsigned short* xlr  = (unsigned short*)alloc((size_t)N_NODES * 1024 * 2);
  unsigned short* sab  = (unsigned short*)alloc((size_t)N_NODES * 256 * 2);
  float* pool = (float*)alloc((size_t)N_NODES * 128 * 4);
  unsigned short* WlrT = (unsigned short*)alloc((size_t)4 * 1024 * 128 * 2);
  unsigned short* W1T  = (unsigned short*)alloc((size_t)256 * 128 * 2);
  unsigned short* W2T  = (unsigned short*)alloc((size_t)128 * 128 * 2);
  unsigned short* gWT  = (unsigned short*)alloc((size_t)128 * 128 * 2);
  int* degD = (int*)alloc((size_t)N_NODES * 4);
  int* degS = (int*)alloc((size_t)N_NODES * 4);
  int* offD = (int*)alloc((size_t)(N_NODES + 1) * 4);
  int* offS = (int*)alloc((size_t)(N_NODES + 1) * 4);
  int* curD = (int*)alloc((size_t)N_NODES * 4);
  int* curS = (int*)alloc((size_t)N_NODES * 4);
  int* eidD = (int*)alloc((size_t)N_EDGES * 4);
  int* eidS = (int*)alloc((size_t)N_EDGES * 4);

  hipMemsetAsync(degD, 0, (size_t)N_NODES * 4, stream);
  hipMemsetAsync(degS, 0, (size_t)N_NODES * 4, stream);
  hipMemsetAsync(pool, 0, (size_t)N_NODES * 128 * 4, stream);

  pack_kernel<<<(589824 + 255) / 256, 256, 0, stream>>>(gWl, gWr, spW1, spW2, spGW,
                                                        WlrT, W1T, W2T, gWT);
  embed_kernel<<<(N_NODES * 128) / 256, 256, 0, stream>>>(x, embW, embB, hA, hbfA);
  hist_kernel<<<(N_EDGES + 255) / 256, 256, 0, stream>>>(ei, degD, degS);
  scan_kernel<<<1, 1024, 0, stream>>>(degD, offD, curD, degS, offS, curS, N_NODES);
  scatter_kernel<<<(N_EDGES + 255) / 256, 256, 0, stream>>>(ei, curD, curS, eidD, eidS);

  const int MB64 = (N_NODES + 63) / 64;   // 157
  float* hcur = hA; float* hnext = hB;
  unsigned short* hbcur = hbfA; unsigned short* hbnext = hbfB;
  for (int l = 0; l < LAYERS; ++l) {
    mfma_gemm_kernel<<<dim3(16, MB64), 256, 0, stream>>>(
        hbcur, WlrT + (size_t)l * 1024 * 128, xlr, N_NODES, 1024);
    gat_agg_kernel<<<N_NODES, 256, 0, stream>>>(hcur, hnext, hbnext, xlr, ei, eattr,
                                                offD, eidD,
                                                gWe + (size_t)l * EDIM * HC,
                                                gAtt + (size_t)l * HC,
                                                gB + (size_t)l * 128,
                                                lnG + (size_t)l * 128,
                                                lnB + (size_t)l * 128);
    float* t1 = hcur; hcur = hnext; hnext = t1;
    unsigned short* t2 = hbcur; hbcur = hbnext; hbnext = t2;
  }
  mfma_gemm_kernel<<<dim3(4, MB64), 256, 0, stream>>>(hbcur, W1T, sab, N_NODES, 256);
  sp_edge_kernel<<<(N_EDGES + 63) / 64, 256, 0, stream>>>(sab, spB1, W2T, spB2, gWT,
                                                          spGB, ei, eidS, pool);
  finalize_kernel<<<(N_NODES + 3) / 4, 256, 0, stream>>>(hcur, pool, degS, fnG, fnB, out);
}

// Round 3
// 945.539 us; speedup vs baseline: 2.2576x; 1.1052x over previous
//
#include <hip/hip_runtime.h>
#include <hip/hip_bf16.h>
#include <math.h>

#define N_NODES 10000
#define N_EDGES 320000
#define HEADS   4
#define CDIM    128
#define HC      512
#define LAYERS  4
#define DIN     7
#define EDIM    5

typedef short short8 __attribute__((ext_vector_type(8)));
typedef unsigned short us8 __attribute__((ext_vector_type(8)));
typedef float f32x4 __attribute__((ext_vector_type(4)));

__device__ __forceinline__ void atomAddF(float* p, float v) { unsafeAtomicAdd(p, v); }

__device__ __forceinline__ unsigned short f2bf(float f) {
  unsigned u = __float_as_uint(f);
  unsigned r = u + 0x7fffu + ((u >> 16) & 1u);
  return (unsigned short)(r >> 16);
}
__device__ __forceinline__ float bf2f(unsigned short u) {
  return __uint_as_float(((unsigned)u) << 16);
}

// ---------------- embed: h = relu(x @ embW + embB), fp32 + bf16 copies ----------------
__global__ __launch_bounds__(256) void embed_kernel(
    const float* __restrict__ x, const float* __restrict__ W,
    const float* __restrict__ b, float* __restrict__ h, unsigned short* __restrict__ hbf)
{
  int t = blockIdx.x * 256 + threadIdx.x;
  int n = t >> 7, c = t & 127;
  float acc = b[c];
#pragma unroll
  for (int k = 0; k < DIN; ++k) acc += x[n * DIN + k] * W[k * CDIM + c];
  acc = fmaxf(acc, 0.f);
  h[t] = acc;
  hbf[t] = f2bf(acc);
}

// ---------------- weight pack: bf16 + transpose ----------------
__global__ __launch_bounds__(256) void pack_kernel(
    const float* __restrict__ Wl, const float* __restrict__ Wr,
    const float* __restrict__ W1, const float* __restrict__ W2,
    const float* __restrict__ gW, unsigned short* __restrict__ WlrT,
    unsigned short* __restrict__ W1T, unsigned short* __restrict__ W2T,
    unsigned short* __restrict__ gWT)
{
  int t = blockIdx.x * 256 + threadIdx.x;
  if (t < 524288) {                       // 4*1024*128
    int k = t & 127, n = (t >> 7) & 1023, l = t >> 17;
    float v = (n < 512) ? Wl[(size_t)(l * 128 + k) * 512 + n]
                        : Wr[(size_t)(l * 128 + k) * 512 + (n - 512)];
    WlrT[t] = f2bf(v);
  } else if (t < 524288 + 32768) {        // 256*128
    int u = t - 524288; int k = u & 127, n = u >> 7;
    float v = (n < 128) ? W1[k * 128 + n] : W1[(128 + k) * 128 + (n - 128)];
    W1T[u] = f2bf(v);
  } else if (t < 557056 + 16384) {
    int u = t - 557056; int k = u & 127, n = u >> 7;
    W2T[u] = f2bf(W2[k * 128 + n]);
  } else if (t < 573440 + 16384) {
    int u = t - 573440; int k = u & 127, n = u >> 7;
    gWT[u] = f2bf(gW[k * 128 + n]);
  }
}

// ---------------- degree histogram ----------------
__global__ __launch_bounds__(256) void hist_kernel(
    const int* __restrict__ ei, int* __restrict__ degD, int* __restrict__ degS)
{
  int e = blockIdx.x * 256 + threadIdx.x;
  if (e < N_EDGES) {
    atomicAdd(&degS[ei[e]], 1);
    atomicAdd(&degD[ei[N_EDGES + e]], 1);
  }
}

// ---------------- exclusive scan ----------------
__global__ __launch_bounds__(1024) void scan_kernel(
    const int* __restrict__ degD, int* __restrict__ offD, int* __restrict__ curD,
    const int* __restrict__ degS, int* __restrict__ offS, int* __restrict__ curS, int n)
{
  __shared__ int wsum[16];
  __shared__ int carry;
  int tid = threadIdx.x, wid = tid >> 6, lane = tid & 63;
  for (int arr = 0; arr < 2; ++arr) {
    const int* deg = arr ? degS : degD;
    int* off = arr ? offS : offD;
    int* cur = arr ? curS : curD;
    if (tid == 0) carry = 0;
    __syncthreads();
    for (int base = 0; base < n; base += 1024) {
      int i = base + tid;
      int v = (i < n) ? deg[i] : 0;
      int incl = v;
#pragma unroll
      for (int o = 1; o < 64; o <<= 1) {
        int t2 = __shfl_up(incl, o);
        if (lane >= o) incl += t2;
      }
      if (lane == 63) wsum[wid] = incl;
      __syncthreads();
      if (tid < 16) {
        int wv = wsum[tid];
#pragma unroll
        for (int o = 1; o < 16; o <<= 1) {
          int t2 = __shfl_up(wv, o);
          if (tid >= o) wv += t2;
        }
        wsum[tid] = wv;
      }
      __syncthreads();
      int woff = (wid > 0) ? wsum[wid - 1] : 0;
      int excl = carry + woff + incl - v;
      if (i < n) { off[i] = excl; cur[i] = excl; }
      __syncthreads();
      if (tid == 0) carry += wsum[15];
      __syncthreads();
    }
    if (tid == 0) off[n] = carry;
    __syncthreads();
  }
}

// ---------------- CSR scatter ----------------
__global__ __launch_bounds__(256) void scatter_kernel(
    const int* __restrict__ ei, int* __restrict__ curD, int* __restrict__ curS,
    int* __restrict__ eidD, int* __restrict__ eidS)
{
  int e = blockIdx.x * 256 + threadIdx.x;
  if (e < N_EDGES) {
    int s = ei[e], d = ei[N_EDGES + e];
    int p = atomicAdd(&curD[d], 1);
    eidD[p] = e;
    int q = atomicAdd(&curS[s], 1);
    eidS[q] = e;
  }
}

// ---------------- bf16 MFMA GEMM: C[M,N](bf16) = A[M,128] @ BT[N,128]^T ----
__global__ __launch_bounds__(256) void mfma_gemm_kernel(
    const unsigned short* __restrict__ A, const unsigned short* __restrict__ BT,
    unsigned short* __restrict__ C, int M, int ldc)
{
  __shared__ __align__(16) unsigned short sA[64 * 128];
  __shared__ __align__(16) unsigned short sB[64 * 128];
  int tid = threadIdx.x;
  int bm = blockIdx.y * 64, bn = blockIdx.x * 64;
#pragma unroll
  for (int i = 0; i < 4; ++i) {
    int ch = tid + i * 256;            // 1024 chunks of 16B
    int r = ch >> 4, kc = ch & 15;
    int gr = bm + r;
    short8 v = {0, 0, 0, 0, 0, 0, 0, 0};
    if (gr < M) v = *(const short8*)&A[(size_t)gr * 128 + kc * 8];
    *(short8*)&sA[r * 128 + ((kc ^ (r & 7)) * 8)] = v;
  }
#pragma unroll
  for (int i = 0; i < 4; ++i) {
    int ch = tid + i * 256;
    int r = ch >> 4, kc = ch & 15;
    short8 v = *(const short8*)&BT[(size_t)(bn + r) * 128 + kc * 8];
    *(short8*)&sB[r * 128 + ((kc ^ (r & 7)) * 8)] = v;
  }
  __syncthreads();
  int w = tid >> 6, lane = tid & 63;
  int wr = (w >> 1) * 32, wc = (w & 1) * 32;
  int l15 = lane & 15, q = lane >> 4;
  f32x4 acc00 = {0, 0, 0, 0}, acc01 = acc00, acc10 = acc00, acc11 = acc00;
#pragma unroll
  for (int ks = 0; ks < 4; ++ks) {
    int c0 = ks * 4 + q;
    int m0 = wr + l15, m1 = m0 + 16;
    int n0 = wc + l15, n1 = n0 + 16;
    short8 a0 = *(const short8*)&sA[m0 * 128 + ((c0 ^ (m0 & 7)) * 8)];
    short8 a1 = *(const short8*)&sA[m1 * 128 + ((c0 ^ (m1 & 7)) * 8)];
    short8 b0 = *(const short8*)&sB[n0 * 128 + ((c0 ^ (n0 & 7)) * 8)];
    short8 b1 = *(const short8*)&sB[n1 * 128 + ((c0 ^ (n1 & 7)) * 8)];
    acc00 = __builtin_amdgcn_mfma_f32_16x16x32_bf16(a0, b0, acc00, 0, 0, 0);
    acc01 = __builtin_amdgcn_mfma_f32_16x16x32_bf16(a0, b1, acc01, 0, 0, 0);
    acc10 = __builtin_amdgcn_mfma_f32_16x16x32_bf16(a1, b0, acc10, 0, 0, 0);
    acc11 = __builtin_amdgcn_mfma_f32_16x16x32_bf16(a1, b1, acc11, 0, 0, 0);
  }
#pragma unroll
  for (int mf = 0; mf < 2; ++mf) {
#pragma unroll
    for (int nf = 0; nf < 2; ++nf) {
      f32x4 acc = mf == 0 ? (nf == 0 ? acc00 : acc01) : (nf == 0 ? acc10 : acc11);
      int col = bn + wc + nf * 16 + l15;
#pragma unroll
      for (int r = 0; r < 4; ++r) {
        int row = bm + wr + mf * 16 + 4 * q + r;
        if (row < M) C[(size_t)row * ldc + col] = f2bf(acc[r]);
      }
    }
  }
}

// ---------------- GATv2 aggregation: 1 wave per node, 4 nodes/block ----------------
// lane owns 8 of 512 (h,c); 16-lane group = 1 head. Fused relu+residual+LN.
__global__ __launch_bounds__(256) void gat_agg_kernel(
    const float* __restrict__ h_in, float* __restrict__ h_out,
    unsigned short* __restrict__ hbf_out, const unsigned short* __restrict__ xlr,
    const int* __restrict__ ei, const float* __restrict__ eattr,
    const int* __restrict__ offD, const int* __restrict__ eidD,
    const float* __restrict__ We, const float* __restrict__ att,
    const float* __restrict__ gbias, const float* __restrict__ lng,
    const float* __restrict__ lnb)
{
  __shared__ float sWe[EDIM * HC];   // 10KB
  __shared__ float sAtt[HC];         // 2KB
  int tid = threadIdx.x;
  for (int i = tid; i < EDIM * HC; i += 256) sWe[i] = We[i];
  for (int i = tid; i < HC; i += 256) sAtt[i] = att[i];
  __syncthreads();

  int w = tid >> 6, lane = tid & 63;
  int n = blockIdx.x * 4 + w;
  int base = lane * 8;

  float xr_reg[8];
  {
    us8 u = *(const us8*)&xlr[(size_t)n * 1024 + 512 + base];
#pragma unroll
    for (int j = 0; j < 8; ++j) xr_reg[j] = bf2f(u[j]);
  }
  float wAtt[8];
#pragma unroll
  for (int j = 0; j < 8; ++j) wAtt[j] = sAtt[base + j];

  float m = -INFINITY, dsum = 0.f;
  float acc[8] = {0.f, 0.f, 0.f, 0.f, 0.f, 0.f, 0.f, 0.f};
  int e0 = offD[n], e1 = offD[n + 1];

  // one-ahead prefetch of edge id / src / attrs
  int e_nx = (e0 < e1) ? eidD[e0] : 0;
  int s_nx = (e0 < e1) ? ei[e_nx] : 0;
  float4 eaA_nx; float eaB_nx;
  if (e0 < e1) {
    eaA_nx = *(const float4*)&eattr[(size_t)e_nx * 5];
    eaB_nx = eattr[(size_t)e_nx * 5 + 4];
  }
  for (int idx = e0; idx < e1; ++idx) {
    int s = s_nx;
    float ea0 = eaA_nx.x, ea1 = eaA_nx.y, ea2 = eaA_nx.z, ea3 = eaA_nx.w, ea4 = eaB_nx;
    us8 u = *(const us8*)&xlr[(size_t)s * 1024 + base];
    if (idx + 1 < e1) {
      e_nx = eidD[idx + 1];
      s_nx = ei[e_nx];
      eaA_nx = *(const float4*)&eattr[(size_t)e_nx * 5];
      eaB_nx = eattr[(size_t)e_nx * 5 + 4];
    }
    float xlv[8];
#pragma unroll
    for (int j = 0; j < 8; ++j) xlv[j] = bf2f(u[j]);
    float logit = 0.f;
#pragma unroll
    for (int j = 0; j < 8; ++j) {
      float v = xlv[j] + xr_reg[j]
              + ea0 * sWe[base + j] + ea1 * sWe[HC + base + j]
              + ea2 * sWe[2 * HC + base + j] + ea3 * sWe[3 * HC + base + j]
              + ea4 * sWe[4 * HC + base + j];
      v = (v > 0.f) ? v : 0.2f * v;
      logit += v * wAtt[j];
    }
    logit += __shfl_xor(logit, 1);
    logit += __shfl_xor(logit, 2);
    logit += __shfl_xor(logit, 4);
    logit += __shfl_xor(logit, 8);       // per-16-lane-group (= per-head) dot
    float nm = fmaxf(m, logit);
    float sc = expf(m - nm);
    float p = expf(logit - nm);
    dsum = dsum * sc + p;
#pragma unroll
    for (int j = 0; j < 8; ++j) acc[j] = acc[j] * sc + p * xlv[j];
    m = nm;
  }

  // normalize per head, head-average via shfl, fused bias/relu/residual/LN
  float inv = (dsum > 0.f) ? (1.f / dsum) : 0.f;
  int c8 = (lane & 15) * 8;            // this lane's 8 output cols
  float o[8];
  float s1 = 0.f, s2 = 0.f;
#pragma unroll
  for (int j = 0; j < 8; ++j) {
    float v = acc[j] * inv;
    v += __shfl_xor(v, 16);
    v += __shfl_xor(v, 32);            // sum over 4 heads (replicated in all groups)
    float oo = 0.25f * v + gbias[c8 + j];
    oo = fmaxf(oo, 0.f);
    oo += h_in[(size_t)n * 128 + c8 + j];
    o[j] = oo;
    s1 += oo; s2 += oo * oo;
  }
  // all 4 groups hold identical copies -> reduce over full wave, scale by 1/512
  s1 += __shfl_xor(s1, 1);  s2 += __shfl_xor(s2, 1);
  s1 += __shfl_xor(s1, 2);  s2 += __shfl_xor(s2, 2);
  s1 += __shfl_xor(s1, 4);  s2 += __shfl_xor(s2, 4);
  s1 += __shfl_xor(s1, 8);  s2 += __shfl_xor(s2, 8);
  s1 += __shfl_xor(s1, 16); s2 += __shfl_xor(s2, 16);
  s1 += __shfl_xor(s1, 32); s2 += __shfl_xor(s2, 32);
  float mean = s1 * (1.f / 512.f);
  float var = s2 * (1.f / 512.f) - mean * mean;
  float rs = rsqrtf(var + 1e-5f);
  if (lane < 16) {
#pragma unroll
    for (int j = 0; j < 8; ++j) {
      float val = (o[j] - mean) * rs * lng[c8 + j] + lnb[c8 + j];
      h_out[(size_t)n * 128 + c8 + j] = val;
      hbf_out[(size_t)n * 128 + c8 + j] = f2bf(val);
    }
  }
}

// ---------------- social pool edge kernel (bf16 MFMA) ----------------
__global__ __launch_bounds__(256) void sp_edge_kernel(
    const unsigned short* __restrict__ sab, const float* __restrict__ b1,
    const unsigned short* __restrict__ W2T, const float* __restrict__ b2,
    const unsigned short* __restrict__ gWT, const float* __restrict__ gb,
    const int* __restrict__ ei, const int* __restrict__ eidS,
    float* __restrict__ pool)
{
  __shared__ __align__(16) unsigned short sT[64 * 128];   // 16KB A-operand (swizzled)
  __shared__ __align__(16) float sU[128 * 65];            // 33.3KB: B-operand / gatedT
  __shared__ int rsrc[64];
  __shared__ int rdst[64];
  unsigned short* sB = (unsigned short*)sU;               // 128x128 bf16 (swizzled)
  int tid = threadIdx.x;
  int ebase = blockIdx.x * 64;
  if (tid < 64) {
    int idx = ebase + tid;
    int s = -1, d = 0;
    if (idx < N_EDGES) { int e = eidS[idx]; s = ei[e]; d = ei[N_EDGES + e]; }
    rsrc[tid] = s; rdst[tid] = d;
  }
  __syncthreads();

#pragma unroll
  for (int i = 0; i < 4; ++i) {
    int ch = tid + i * 256;
    int r = ch >> 4, kc = ch & 15, c0 = kc * 8;
    int s = rsrc[r];
    short8 o = {0, 0, 0, 0, 0, 0, 0, 0};
    if (s >= 0) {
      int d = rdst[r];
      us8 ua = *(const us8*)&sab[(size_t)s * 256 + c0];
      us8 ub = *(const us8*)&sab[(size_t)d * 256 + 128 + c0];
      float4 bb0 = *(const float4*)&b1[c0];
      float4 bb1 = *(const float4*)&b1[c0 + 4];
      float bv[8] = {bb0.x, bb0.y, bb0.z, bb0.w, bb1.x, bb1.y, bb1.z, bb1.w};
#pragma unroll
      for (int j = 0; j < 8; ++j)
        o[j] = (short)f2bf(fmaxf(bf2f(ua[j]) + bf2f(ub[j]) + bv[j], 0.f));
    }
    *(short8*)&sT[r * 128 + ((kc ^ (r & 7)) * 8)] = o;
  }
#pragma unroll
  for (int i = 0; i < 8; ++i) {
    int ch = tid + i * 256;
    int n = ch >> 4, kc = ch & 15;
    short8 v = *(const short8*)&W2T[(size_t)n * 128 + kc * 8];
    *(short8*)&sB[n * 128 + ((kc ^ (n & 7)) * 8)] = v;
  }
  __syncthreads();

  int w = tid >> 6, lane = tid & 63;
  int r0 = w * 16;
  int l15 = lane & 15, q = lane >> 4;

  f32x4 acc1[8], acc2[8];
#pragma unroll
  for (int i = 0; i < 8; ++i) { acc1[i] = (f32x4){0, 0, 0, 0}; acc2[i] = acc1[i]; }
  {
    short8 a[4];
#pragma unroll
    for (int ks = 0; ks < 4; ++ks) {
      int m = r0 + l15;
      a[ks] = *(const short8*)&sT[m * 128 + (((ks * 4 + q) ^ (m & 7)) * 8)];
    }
#pragma unroll
    for (int nf = 0; nf < 8; ++nf) {
      int n = nf * 16 + l15;
#pragma unroll
      for (int ks = 0; ks < 4; ++ks) {
        short8 b = *(const short8*)&sB[n * 128 + (((ks * 4 + q) ^ (n & 7)) * 8)];
        acc1[nf] = __builtin_amdgcn_mfma_f32_16x16x32_bf16(a[ks], b, acc1[nf], 0, 0, 0);
      }
    }
  }
#pragma unroll
  for (int nf = 0; nf < 8; ++nf) {
    float bias = b2[nf * 16 + l15];
#pragma unroll
    for (int r = 0; r < 4; ++r) acc1[nf][r] += bias;
  }
  __syncthreads();

#pragma unroll
  for (int nf = 0; nf < 8; ++nf) {
    int colN = nf * 16 + l15;
    int kc = colN >> 3, j = colN & 7;
#pragma unroll
    for (int r = 0; r < 4; ++r) {
      int row = r0 + 4 * q + r;
      sT[row * 128 + ((kc ^ (row & 7)) * 8) + j] = f2bf(acc1[nf][r]);
    }
  }
#pragma unroll
  for (int i = 0; i < 8; ++i) {
    int ch = tid + i * 256;
    int n = ch >> 4, kc = ch & 15;
    short8 v = *(const short8*)&gWT[(size_t)n * 128 + kc * 8];
    *(short8*)&sB[n * 128 + ((kc ^ (n & 7)) * 8)] = v;
  }
  __syncthreads();

  {
    short8 a[4];
#pragma unroll
    for (int ks = 0; ks < 4; ++ks) {
      int m = r0 + l15;
      a[ks] = *(const short8*)&sT[m * 128 + (((ks * 4 + q) ^ (m & 7)) * 8)];
    }
#pragma unroll
    for (int nf = 0; nf < 8; ++nf) {
      int n = nf * 16 + l15;
#pragma unroll
      for (int ks = 0; ks < 4; ++ks) {
        short8 b = *(const short8*)&sB[n * 128 + (((ks * 4 + q) ^ (n & 7)) * 8)];
        acc2[nf] = __builtin_amdgcn_mfma_f32_16x16x32_bf16(a[ks], b, acc2[nf], 0, 0, 0);
      }
    }
  }
  __syncthreads();

  float* gT = sU;
#pragma unroll
  for (int nf = 0; nf < 8; ++nf) {
    int colN = nf * 16 + l15;
    float gbias = gb[colN];
#pragma unroll
    for (int r = 0; r < 4; ++r) {
      float g = acc2[nf][r] + gbias;
      float gate = 1.f / (1.f + expf(-g));
      int row = r0 + 4 * q + r;
      gT[colN * 65 + row] = acc1[nf][r] * gate;
    }
  }
  __syncthreads();

  {
    int c = tid & 127, half = tid >> 7;
    int rbeg = half * 32, rend = rbeg + 32;
    int curs = -1; float run = 0.f;
    for (int r = rbeg; r < rend; ++r) {
      int s = rsrc[r];
      if (s != curs) {
        if (curs >= 0) atomAddF(&pool[(size_t)curs * 128 + c], run);
        curs = s; run = 0.f;
      }
      if (s >= 0) run += gT[c * 65 + r];
    }
    if (curs >= 0) atomAddF(&pool[(size_t)curs * 128 + c], run);
  }
}

// ---------------- finalize: out = LN(h + pool/max(cnt,1)) ----------------
__global__ __launch_bounds__(256) void finalize_kernel(
    const float* __restrict__ h, const float* __restrict__ pool,
    const int* __restrict__ degS, const float* __restrict__ g,
    const float* __restrict__ b, float* __restrict__ out)
{
  int t = blockIdx.x * 256 + threadIdx.x;
  int n = t >> 6, lane = t & 63;
  if (n >= N_NODES) return;
  float cnt = fmaxf((float)degS[n], 1.f);
  float a = h[(size_t)n * 128 + lane] + pool[(size_t)n * 128 + lane] / cnt;
  float c2 = h[(size_t)n * 128 + 64 + lane] + pool[(size_t)n * 128 + 64 + lane] / cnt;
  float s = a + c2, s2 = a * a + c2 * c2;
#pragma unroll
  for (int o = 1; o < 64; o <<= 1) { s += __shfl_xor(s, o); s2 += __shfl_xor(s2, o); }
  float mean = s * (1.f / 128.f);
  float var = s2 * (1.f / 128.f) - mean * mean;
  float rs = rsqrtf(var + 1e-5f);
  out[(size_t)n * 128 + lane] = (a - mean) * rs * g[lane] + b[lane];
  out[(size_t)n * 128 + 64 + lane] = (c2 - mean) * rs * g[64 + lane] + b[64 + lane];
}

// ---------------- host ----------------
extern "C" void kernel_launch(void* const* d_in, const int* in_sizes, int n_in,
                              void* d_out, int out_size, void* d_ws, size_t ws_size,
                              hipStream_t stream) {
  (void)in_sizes; (void)n_in; (void)out_size; (void)ws_size;
  const float* x     = (const float*)d_in[0];
  const int*   ei    = (const int*)d_in[1];
  const float* eattr = (const float*)d_in[2];
  const float* embW  = (const float*)d_in[3];
  const float* embB  = (const float*)d_in[4];
  const float* gWl   = (const float*)d_in[5];
  const float* gWr   = (const float*)d_in[6];
  const float* gWe   = (const float*)d_in[7];
  const float* gAtt  = (const float*)d_in[8];
  const float* gB    = (const float*)d_in[9];
  const float* lnG   = (const float*)d_in[10];
  const float* lnB   = (const float*)d_in[11];
  const float* spW1  = (const float*)d_in[12];
  const float* spB1  = (const float*)d_in[13];
  const float* spW2  = (const float*)d_in[14];
  const float* spB2  = (const float*)d_in[15];
  const float* spGW  = (const float*)d_in[16];
  const float* spGB  = (const float*)d_in[17];
  const float* fnG   = (const float*)d_in[18];
  const float* fnB   = (const float*)d_in[19];
  float* out = (float*)d_out;

  char* ws = (char*)d_ws;
  size_t off = 0;
  auto alloc = [&](size_t bytes) {
    void* p = ws + off;
    off = (off + bytes + 255) & ~(size_t)255;
    return p;
  };
  float* hA   = (float*)alloc((size_t)N_NODES * 128 * 4);
  float* hB   = (float*)alloc((size_t)N_NODES * 128 * 4);
  unsigned short* hbfA = (unsigned short*)alloc((size_t)N_NODES * 128 * 2);
  unsigned short* hbfB = (unsigned short*)alloc((size_t)N_NODES * 128 * 2);
  unsigned short* xlr  = (unsigned short*)alloc((size_t)N_NODES * 1024 * 2);
  unsigned short* sab  = (unsigned short*)alloc((size_t)N_NODES * 256 * 2);
  float* pool = (float*)alloc((size_t)N_NODES * 128 * 4);
  unsigned short* WlrT = (unsigned short*)alloc((size_t)4 * 1024 * 128 * 2);
  unsigned short* W1T  = (unsigned short*)alloc((size_t)256 * 128 * 2);
  unsigned short* W2T  = (unsigned short*)alloc((size_t)128 * 128 * 2);
  unsigned short* gWT  = (unsigned short*)alloc((size_t)128 * 128 * 2);
  int* degD = (int*)alloc((size_t)N_NODES * 4);
  int* degS = (int*)alloc((size_t)N_NODES * 4);
  int* offD = (int*)alloc((size_t)(N_NODES + 1) * 4);
  int* offS = (int*)alloc((size_t)(N_NODES + 1) * 4);
  int* curD = (int*)alloc((size_t)N_NODES * 4);
  int* curS = (int*)alloc((size_t)N_NODES * 4);
  int* eidD = (int*)alloc((size_t)N_EDGES * 4);
  int* eidS = (int*)alloc((size_t)N_EDGES * 4);

  hipMemsetAsync(degD, 0, (size_t)N_NODES * 4, stream);
  hipMemsetAsync(degS, 0, (size_t)N_NODES * 4, stream);
  hipMemsetAsync(pool, 0, (size_t)N_NODES * 128 * 4, stream);

  pack_kernel<<<(589824 + 255) / 256, 256, 0, stream>>>(gWl, gWr, spW1, spW2, spGW,
                                                        WlrT, W1T, W2T, gWT);
  embed_kernel<<<(N_NODES * 128) / 256, 256, 0, stream>>>(x, embW, embB, hA, hbfA);
  hist_kernel<<<(N_EDGES + 255) / 256, 256, 0, stream>>>(ei, degD, degS);
  scan_kernel<<<1, 1024, 0, stream>>>(degD, offD, curD, degS, offS, curS, N_NODES);
  scatter_kernel<<<(N_EDGES + 255) / 256, 256, 0, stream>>>(ei, curD, curS, eidD, eidS);

  const int MB64 = (N_NODES + 63) / 64;   // 157
  float* hcur = hA; float* hnext = hB;
  unsigned short* hbcur = hbfA; unsigned short* hbnext = hbfB;
  for (int l = 0; l < LAYERS; ++l) {
    mfma_gemm_kernel<<<dim3(16, MB64), 256, 0, stream>>>(
        hbcur, WlrT + (size_t)l * 1024 * 128, xlr, N_NODES, 1024);
    gat_agg_kernel<<<(N_NODES + 3) / 4, 256, 0, stream>>>(hcur, hnext, hbnext, xlr, ei, eattr,
                                                          offD, eidD,
                                                          gWe + (size_t)l * EDIM * HC,
                                                          gAtt + (size_t)l * HC,
                                                          gB + (size_t)l * 128,
                                                          lnG + (size_t)l * 128,
                                                          lnB + (size_t)l * 128);
    float* t1 = hcur; hcur = hnext; hnext = t1;
    unsigned short* t2 = hbcur; hbcur = hbnext; hbnext = t2;
  }
  mfma_gemm_kernel<<<dim3(4, MB64), 256, 0, stream>>>(hbcur, W1T, sab, N_NODES, 256);
  sp_edge_kernel<<<(N_EDGES + 63) / 64, 256, 0, stream>>>(sab, spB1, W2T, spB2, gWT,
                                                          spGB, ei, eidS, pool);
  finalize_kernel<<<(N_NODES + 3) / 4, 256, 0, stream>>>(hcur, pool, degS, fnG, fnB, out);
}

// Round 5
// 720.873 us; speedup vs baseline: 2.9612x; 1.3117x over previous
//
#include <hip/hip_runtime.h>
#include <hip/hip_bf16.h>
#include <math.h>

#define N_NODES 10000
#define N_EDGES 320000
#define HEADS   4
#define CDIM    128
#define HC      512
#define LAYERS  4
#define DIN     7
#define EDIM    5

typedef short short8 __attribute__((ext_vector_type(8)));
typedef unsigned short us8 __attribute__((ext_vector_type(8)));
typedef float f32x4 __attribute__((ext_vector_type(4)));

__device__ __forceinline__ void atomAddF(float* p, float v) { unsafeAtomicAdd(p, v); }

__device__ __forceinline__ unsigned short f2bf(float f) {
  unsigned u = __float_as_uint(f);
  unsigned r = u + 0x7fffu + ((u >> 16) & 1u);
  return (unsigned short)(r >> 16);
}
__device__ __forceinline__ float bf2f(unsigned short u) {
  return __uint_as_float(((unsigned)u) << 16);
}

// ---------------- embed: h = relu(x @ embW + embB), fp32 + bf16 copies ----------------
__global__ __launch_bounds__(256) void embed_kernel(
    const float* __restrict__ x, const float* __restrict__ W,
    const float* __restrict__ b, float* __restrict__ h, unsigned short* __restrict__ hbf)
{
  int t = blockIdx.x * 256 + threadIdx.x;
  int n = t >> 7, c = t & 127;
  float acc = b[c];
#pragma unroll
  for (int k = 0; k < DIN; ++k) acc += x[n * DIN + k] * W[k * CDIM + c];
  acc = fmaxf(acc, 0.f);
  h[t] = acc;
  hbf[t] = f2bf(acc);
}

// ---------------- weight pack: bf16 + transpose ----------------
__global__ __launch_bounds__(256) void pack_kernel(
    const float* __restrict__ Wl, const float* __restrict__ Wr,
    const float* __restrict__ W1, const float* __restrict__ W2,
    const float* __restrict__ gW, unsigned short* __restrict__ WlrT,
    unsigned short* __restrict__ W1T, unsigned short* __restrict__ W2T,
    unsigned short* __restrict__ gWT)
{
  int t = blockIdx.x * 256 + threadIdx.x;
  if (t < 524288) {                       // 4*1024*128
    int k = t & 127, n = (t >> 7) & 1023, l = t >> 17;
    float v = (n < 512) ? Wl[(size_t)(l * 128 + k) * 512 + n]
                        : Wr[(size_t)(l * 128 + k) * 512 + (n - 512)];
    WlrT[t] = f2bf(v);
  } else if (t < 524288 + 32768) {        // 256*128
    int u = t - 524288; int k = u & 127, n = u >> 7;
    float v = (n < 128) ? W1[k * 128 + n] : W1[(128 + k) * 128 + (n - 128)];
    W1T[u] = f2bf(v);
  } else if (t < 557056 + 16384) {
    int u = t - 557056; int k = u & 127, n = u >> 7;
    W2T[u] = f2bf(W2[k * 128 + n]);
  } else if (t < 573440 + 16384) {
    int u = t - 573440; int k = u & 127, n = u >> 7;
    gWT[u] = f2bf(gW[k * 128 + n]);
  }
}

// ---------------- degree histogram ----------------
__global__ __launch_bounds__(256) void hist_kernel(
    const int* __restrict__ ei, int* __restrict__ degD, int* __restrict__ degS)
{
  int e = blockIdx.x * 256 + threadIdx.x;
  if (e < N_EDGES) {
    atomicAdd(&degS[ei[e]], 1);
    atomicAdd(&degD[ei[N_EDGES + e]], 1);
  }
}

// ---------------- exclusive scan ----------------
__global__ __launch_bounds__(1024) void scan_kernel(
    const int* __restrict__ degD, int* __restrict__ offD, int* __restrict__ curD,
    const int* __restrict__ degS, int* __restrict__ offS, int* __restrict__ curS, int n)
{
  __shared__ int wsum[16];
  __shared__ int carry;
  int tid = threadIdx.x, wid = tid >> 6, lane = tid & 63;
  for (int arr = 0; arr < 2; ++arr) {
    const int* deg = arr ? degS : degD;
    int* off = arr ? offS : offD;
    int* cur = arr ? curS : curD;
    if (tid == 0) carry = 0;
    __syncthreads();
    for (int base = 0; base < n; base += 1024) {
      int i = base + tid;
      int v = (i < n) ? deg[i] : 0;
      int incl = v;
#pragma unroll
      for (int o = 1; o < 64; o <<= 1) {
        int t2 = __shfl_up(incl, o);
        if (lane >= o) incl += t2;
      }
      if (lane == 63) wsum[wid] = incl;
      __syncthreads();
      if (tid < 16) {
        int wv = wsum[tid];
#pragma unroll
        for (int o = 1; o < 16; o <<= 1) {
          int t2 = __shfl_up(wv, o);
          if (tid >= o) wv += t2;
        }
        wsum[tid] = wv;
      }
      __syncthreads();
      int woff = (wid > 0) ? wsum[wid - 1] : 0;
      int excl = carry + woff + incl - v;
      if (i < n) { off[i] = excl; cur[i] = excl; }
      __syncthreads();
      if (tid == 0) carry += wsum[15];
      __syncthreads();
    }
    if (tid == 0) off[n] = carry;
    __syncthreads();
  }
}

// ---------------- CSR scatter ----------------
__global__ __launch_bounds__(256) void scatter_kernel(
    const int* __restrict__ ei, int* __restrict__ curD, int* __restrict__ curS,
    int* __restrict__ eidD, int* __restrict__ eidS)
{
  int e = blockIdx.x * 256 + threadIdx.x;
  if (e < N_EDGES) {
    int s = ei[e], d = ei[N_EDGES + e];
    int p = atomicAdd(&curD[d], 1);
    eidD[p] = e;
    int q = atomicAdd(&curS[s], 1);
    eidS[q] = e;
  }
}

// ---------------- edge reorder into dst-CSR order (run once, reused 4x) --------------
__global__ __launch_bounds__(256) void reorder_kernel(
    const int* __restrict__ ei, const float* __restrict__ eattr,
    const int* __restrict__ eidD, int* __restrict__ esrc,
    float4* __restrict__ ea4, float* __restrict__ ea1)
{
  int idx = blockIdx.x * 256 + threadIdx.x;
  if (idx < N_EDGES) {
    int e = eidD[idx];
    esrc[idx] = ei[e];
    const float* p = &eattr[(size_t)e * 5];
    ea4[idx] = make_float4(p[0], p[1], p[2], p[3]);
    ea1[idx] = p[4];
  }
}

// ---------------- bf16 MFMA GEMM: C[M,N](bf16) = A[M,128] @ BT[N,128]^T ----
__global__ __launch_bounds__(256) void mfma_gemm_kernel(
    const unsigned short* __restrict__ A, const unsigned short* __restrict__ BT,
    unsigned short* __restrict__ C, int M, int ldc)
{
  __shared__ __align__(16) unsigned short sA[64 * 128];
  __shared__ __align__(16) unsigned short sB[64 * 128];
  int tid = threadIdx.x;
  int bm = blockIdx.y * 64, bn = blockIdx.x * 64;
#pragma unroll
  for (int i = 0; i < 4; ++i) {
    int ch = tid + i * 256;            // 1024 chunks of 16B
    int r = ch >> 4, kc = ch & 15;
    int gr = bm + r;
    short8 v = {0, 0, 0, 0, 0, 0, 0, 0};
    if (gr < M) v = *(const short8*)&A[(size_t)gr * 128 + kc * 8];
    *(short8*)&sA[r * 128 + ((kc ^ (r & 7)) * 8)] = v;
  }
#pragma unroll
  for (int i = 0; i < 4; ++i) {
    int ch = tid + i * 256;
    int r = ch >> 4, kc = ch & 15;
    short8 v = *(const short8*)&BT[(size_t)(bn + r) * 128 + kc * 8];
    *(short8*)&sB[r * 128 + ((kc ^ (r & 7)) * 8)] = v;
  }
  __syncthreads();
  int w = tid >> 6, lane = tid & 63;
  int wr = (w >> 1) * 32, wc = (w & 1) * 32;
  int l15 = lane & 15, q = lane >> 4;
  f32x4 acc00 = {0, 0, 0, 0}, acc01 = acc00, acc10 = acc00, acc11 = acc00;
#pragma unroll
  for (int ks = 0; ks < 4; ++ks) {
    int c0 = ks * 4 + q;
    int m0 = wr + l15, m1 = m0 + 16;
    int n0 = wc + l15, n1 = n0 + 16;
    short8 a0 = *(const short8*)&sA[m0 * 128 + ((c0 ^ (m0 & 7)) * 8)];
    short8 a1 = *(const short8*)&sA[m1 * 128 + ((c0 ^ (m1 & 7)) * 8)];
    short8 b0 = *(const short8*)&sB[n0 * 128 + ((c0 ^ (n0 & 7)) * 8)];
    short8 b1 = *(const short8*)&sB[n1 * 128 + ((c0 ^ (n1 & 7)) * 8)];
    acc00 = __builtin_amdgcn_mfma_f32_16x16x32_bf16(a0, b0, acc00, 0, 0, 0);
    acc01 = __builtin_amdgcn_mfma_f32_16x16x32_bf16(a0, b1, acc01, 0, 0, 0);
    acc10 = __builtin_amdgcn_mfma_f32_16x16x32_bf16(a1, b0, acc10, 0, 0, 0);
    acc11 = __builtin_amdgcn_mfma_f32_16x16x32_bf16(a1, b1, acc11, 0, 0, 0);
  }
#pragma unroll
  for (int mf = 0; mf < 2; ++mf) {
#pragma unroll
    for (int nf = 0; nf < 2; ++nf) {
      f32x4 acc = mf == 0 ? (nf == 0 ? acc00 : acc01) : (nf == 0 ? acc10 : acc11);
      int col = bn + wc + nf * 16 + l15;
#pragma unroll
      for (int r = 0; r < 4; ++r) {
        int row = bm + wr + mf * 16 + 4 * q + r;
        if (row < M) C[(size_t)row * ldc + col] = f2bf(acc[r]);
      }
    }
  }
}

// ---------------- GATv2 aggregation: 1 wave/node, zero LDS, pair-pipelined ----------
// lane owns 8 of 512 (h,c); 16-lane group = 1 head. Weights hoisted to VGPRs.
__global__ __launch_bounds__(256) void gat_agg_kernel(
    const float* __restrict__ h_in, float* __restrict__ h_out,
    unsigned short* __restrict__ hbf_out, const unsigned short* __restrict__ xlr,
    const int* __restrict__ esrc, const float4* __restrict__ ea4,
    const float* __restrict__ ea1, const int* __restrict__ offD,
    const float* __restrict__ We, const float* __restrict__ att,
    const float* __restrict__ gbias, const float* __restrict__ lng,
    const float* __restrict__ lnb)
{
  int tid = threadIdx.x;
  int w = tid >> 6, lane = tid & 63;
  int n = blockIdx.x * 4 + w;
  int base = lane * 8;

  // hoist We (5x8) and att (8) into registers: coalesced per-lane loads, L2-hot
  float wWe[5][8];
#pragma unroll
  for (int k = 0; k < 5; ++k) {
    float4 a = *(const float4*)&We[k * HC + base];
    float4 b = *(const float4*)&We[k * HC + base + 4];
    wWe[k][0] = a.x; wWe[k][1] = a.y; wWe[k][2] = a.z; wWe[k][3] = a.w;
    wWe[k][4] = b.x; wWe[k][5] = b.y; wWe[k][6] = b.z; wWe[k][7] = b.w;
  }
  float wAtt[8];
  {
    float4 a = *(const float4*)&att[base];
    float4 b = *(const float4*)&att[base + 4];
    wAtt[0] = a.x; wAtt[1] = a.y; wAtt[2] = a.z; wAtt[3] = a.w;
    wAtt[4] = b.x; wAtt[5] = b.y; wAtt[6] = b.z; wAtt[7] = b.w;
  }
  float xr_reg[8];
  {
    us8 u = *(const us8*)&xlr[(size_t)n * 1024 + 512 + base];
#pragma unroll
    for (int j = 0; j < 8; ++j) xr_reg[j] = bf2f(u[j]);
  }

  int e0 = offD[n], e1 = offD[n + 1];
  float m = -INFINITY, dsum = 0.f;
  float acc[8] = {0.f, 0.f, 0.f, 0.f, 0.f, 0.f, 0.f, 0.f};

  us8 uA = {0, 0, 0, 0, 0, 0, 0, 0}, uB = uA;
  float4 qaA = {0, 0, 0, 0}, qaB = {0, 0, 0, 0};
  float qeA = 0.f, qeB = 0.f;
  int sA1 = 0, sB1 = 0;

  if (e0 < e1) {
    int iB = (e0 + 1 < e1) ? e0 + 1 : e0;
    int sA0 = esrc[e0], sB0 = esrc[iB];
    uA = *(const us8*)&xlr[(size_t)sA0 * 1024 + base];
    uB = *(const us8*)&xlr[(size_t)sB0 * 1024 + base];
    qaA = ea4[e0]; qeA = ea1[e0];
    qaB = ea4[iB]; qeB = ea1[iB];
    int jA = (e0 + 2 < e1) ? e0 + 2 : e0;
    int jB = (e0 + 3 < e1) ? e0 + 3 : e0;
    sA1 = esrc[jA]; sB1 = esrc[jB];
  }

  for (int i = e0; i < e1; i += 2) {
    // capture current pair into floats
    float x0[8], x1[8];
#pragma unroll
    for (int j = 0; j < 8; ++j) { x0[j] = bf2f(uA[j]); x1[j] = bf2f(uB[j]); }
    float a0 = qaA.x, a1 = qaA.y, a2 = qaA.z, a3 = qaA.w, a4 = qeA;
    float b0 = qaB.x, b1 = qaB.y, b2 = qaB.z, b3 = qaB.w, b4 = qeB;

    // prefetch next pair's xl payload (addresses already resident)
    uA = *(const us8*)&xlr[(size_t)sA1 * 1024 + base];
    uB = *(const us8*)&xlr[(size_t)sB1 * 1024 + base];
    // prefetch next pair's attrs + next-next srcs (sequential, L2-hot)
    {
      int jA = (i + 2 < e1) ? i + 2 : e0;
      int jB = (i + 3 < e1) ? i + 3 : e0;
      qaA = ea4[jA]; qeA = ea1[jA];
      qaB = ea4[jB]; qeB = ea1[jB];
      int kA = (i + 4 < e1) ? i + 4 : e0;
      int kB = (i + 5 < e1) ? i + 5 : e0;
      sA1 = esrc[kA]; sB1 = esrc[kB];
    }

    // two independent logits (compiler interleaves the shuffle chains)
    float lg0 = 0.f, lg1 = 0.f;
#pragma unroll
    for (int j = 0; j < 8; ++j) {
      float v0 = x0[j] + xr_reg[j] + a0 * wWe[0][j] + a1 * wWe[1][j]
               + a2 * wWe[2][j] + a3 * wWe[3][j] + a4 * wWe[4][j];
      v0 = (v0 > 0.f) ? v0 : 0.2f * v0;
      lg0 += v0 * wAtt[j];
      float v1 = x1[j] + xr_reg[j] + b0 * wWe[0][j] + b1 * wWe[1][j]
               + b2 * wWe[2][j] + b3 * wWe[3][j] + b4 * wWe[4][j];
      v1 = (v1 > 0.f) ? v1 : 0.2f * v1;
      lg1 += v1 * wAtt[j];
    }
    lg0 += __shfl_xor(lg0, 1); lg1 += __shfl_xor(lg1, 1);
    lg0 += __shfl_xor(lg0, 2); lg1 += __shfl_xor(lg1, 2);
    lg0 += __shfl_xor(lg0, 4); lg1 += __shfl_xor(lg1, 4);
    lg0 += __shfl_xor(lg0, 8); lg1 += __shfl_xor(lg1, 8);
    lg1 = (i + 1 < e1) ? lg1 : -INFINITY;

    // merged online-softmax update for the pair
    float nm = fmaxf(m, fmaxf(lg0, lg1));
    float sc = __expf(m - nm);
    float p0 = __expf(lg0 - nm);
    float p1 = __expf(lg1 - nm);
    dsum = dsum * sc + p0 + p1;
#pragma unroll
    for (int j = 0; j < 8; ++j) acc[j] = (acc[j] * sc + p0 * x0[j]) + p1 * x1[j];
    m = nm;
  }

  // normalize per head, head-average via shfl, fused bias/relu/residual/LN
  float inv = (dsum > 0.f) ? (1.f / dsum) : 0.f;
  int c8 = (lane & 15) * 8;
  float o[8];
  float s1 = 0.f, s2 = 0.f;
#pragma unroll
  for (int j = 0; j < 8; ++j) {
    float v = acc[j] * inv;
    v += __shfl_xor(v, 16);
    v += __shfl_xor(v, 32);            // sum over 4 heads (replicated in all groups)
    float oo = 0.25f * v + gbias[c8 + j];
    oo = fmaxf(oo, 0.f);
    oo += h_in[(size_t)n * 128 + c8 + j];
    o[j] = oo;
    s1 += oo; s2 += oo * oo;
  }
  s1 += __shfl_xor(s1, 1);  s2 += __shfl_xor(s2, 1);
  s1 += __shfl_xor(s1, 2);  s2 += __shfl_xor(s2, 2);
  s1 += __shfl_xor(s1, 4);  s2 += __shfl_xor(s2, 4);
  s1 += __shfl_xor(s1, 8);  s2 += __shfl_xor(s2, 8);
  s1 += __shfl_xor(s1, 16); s2 += __shfl_xor(s2, 16);
  s1 += __shfl_xor(s1, 32); s2 += __shfl_xor(s2, 32);
  float mean = s1 * (1.f / 512.f);
  float var = s2 * (1.f / 512.f) - mean * mean;
  float rs = rsqrtf(var + 1e-5f);
  if (lane < 16) {
#pragma unroll
    for (int j = 0; j < 8; ++j) {
      float val = (o[j] - mean) * rs * lng[c8 + j] + lnb[c8 + j];
      h_out[(size_t)n * 128 + c8 + j] = val;
      hbf_out[(size_t)n * 128 + c8 + j] = f2bf(val);
    }
  }
}

// ---------------- social pool edge kernel (bf16 MFMA) ----------------
__global__ __launch_bounds__(256) void sp_edge_kernel(
    const unsigned short* __restrict__ sab, const float* __restrict__ b1,
    const unsigned short* __restrict__ W2T, const float* __restrict__ b2,
    const unsigned short* __restrict__ gWT, const float* __restrict__ gb,
    const int* __restrict__ ei, const int* __restrict__ eidS,
    float* __restrict__ pool)
{
  __shared__ __align__(16) unsigned short sT[64 * 128];   // 16KB A-operand (swizzled)
  __shared__ __align__(16) float sU[128 * 65];            // 33.3KB: B-operand / gatedT
  __shared__ int rsrc[64];
  __shared__ int rdst[64];
  unsigned short* sB = (unsigned short*)sU;               // 128x128 bf16 (swizzled)
  int tid = threadIdx.x;
  int ebase = blockIdx.x * 64;
  if (tid < 64) {
    int idx = ebase + tid;
    int s = -1, d = 0;
    if (idx < N_EDGES) { int e = eidS[idx]; s = ei[e]; d = ei[N_EDGES + e]; }
    rsrc[tid] = s; rdst[tid] = d;
  }
  __syncthreads();

#pragma unroll
  for (int i = 0; i < 4; ++i) {
    int ch = tid + i * 256;
    int r = ch >> 4, kc = ch & 15, c0 = kc * 8;
    int s = rsrc[r];
    short8 o = {0, 0, 0, 0, 0, 0, 0, 0};
    if (s >= 0) {
      int d = rdst[r];
      us8 ua = *(const us8*)&sab[(size_t)s * 256 + c0];
      us8 ub = *(const us8*)&sab[(size_t)d * 256 + 128 + c0];
      float4 bb0 = *(const float4*)&b1[c0];
      float4 bb1 = *(const float4*)&b1[c0 + 4];
      float bv[8] = {bb0.x, bb0.y, bb0.z, bb0.w, bb1.x, bb1.y, bb1.z, bb1.w};
#pragma unroll
      for (int j = 0; j < 8; ++j)
        o[j] = (short)f2bf(fmaxf(bf2f(ua[j]) + bf2f(ub[j]) + bv[j], 0.f));
    }
    *(short8*)&sT[r * 128 + ((kc ^ (r & 7)) * 8)] = o;
  }
#pragma unroll
  for (int i = 0; i < 8; ++i) {
    int ch = tid + i * 256;
    int n = ch >> 4, kc = ch & 15;
    short8 v = *(const short8*)&W2T[(size_t)n * 128 + kc * 8];
    *(short8*)&sB[n * 128 + ((kc ^ (n & 7)) * 8)] = v;
  }
  __syncthreads();

  int w = tid >> 6, lane = tid & 63;
  int r0 = w * 16;
  int l15 = lane & 15, q = lane >> 4;

  f32x4 acc1[8], acc2[8];
#pragma unroll
  for (int i = 0; i < 8; ++i) { acc1[i] = (f32x4){0, 0, 0, 0}; acc2[i] = acc1[i]; }
  {
    short8 a[4];
#pragma unroll
    for (int ks = 0; ks < 4; ++ks) {
      int m = r0 + l15;
      a[ks] = *(const short8*)&sT[m * 128 + (((ks * 4 + q) ^ (m & 7)) * 8)];
    }
#pragma unroll
    for (int nf = 0; nf < 8; ++nf) {
      int n = nf * 16 + l15;
#pragma unroll
      for (int ks = 0; ks < 4; ++ks) {
        short8 b = *(const short8*)&sB[n * 128 + (((ks * 4 + q) ^ (n & 7)) * 8)];
        acc1[nf] = __builtin_amdgcn_mfma_f32_16x16x32_bf16(a[ks], b, acc1[nf], 0, 0, 0);
      }
    }
  }
#pragma unroll
  for (int nf = 0; nf < 8; ++nf) {
    float bias = b2[nf * 16 + l15];
#pragma unroll
    for (int r = 0; r < 4; ++r) acc1[nf][r] += bias;
  }
  __syncthreads();

#pragma unroll
  for (int nf = 0; nf < 8; ++nf) {
    int colN = nf * 16 + l15;
    int kc = colN >> 3, j = colN & 7;
#pragma unroll
    for (int r = 0; r < 4; ++r) {
      int row = r0 + 4 * q + r;
      sT[row * 128 + ((kc ^ (row & 7)) * 8) + j] = f2bf(acc1[nf][r]);
    }
  }
#pragma unroll
  for (int i = 0; i < 8; ++i) {
    int ch = tid + i * 256;
    int n = ch >> 4, kc = ch & 15;
    short8 v = *(const short8*)&gWT[(size_t)n * 128 + kc * 8];
    *(short8*)&sB[n * 128 + ((kc ^ (n & 7)) * 8)] = v;
  }
  __syncthreads();

  {
    short8 a[4];
#pragma unroll
    for (int ks = 0; ks < 4; ++ks) {
      int m = r0 + l15;
      a[ks] = *(const short8*)&sT[m * 128 + (((ks * 4 + q) ^ (m & 7)) * 8)];
    }
#pragma unroll
    for (int nf = 0; nf < 8; ++nf) {
      int n = nf * 16 + l15;
#pragma unroll
      for (int ks = 0; ks < 4; ++ks) {
        short8 b = *(const short8*)&sB[n * 128 + (((ks * 4 + q) ^ (n & 7)) * 8)];
        acc2[nf] = __builtin_amdgcn_mfma_f32_16x16x32_bf16(a[ks], b, acc2[nf], 0, 0, 0);
      }
    }
  }
  __syncthreads();

  float* gT = sU;
#pragma unroll
  for (int nf = 0; nf < 8; ++nf) {
    int colN = nf * 16 + l15;
    float gbias = gb[colN];
#pragma unroll
    for (int r = 0; r < 4; ++r) {
      float g = acc2[nf][r] + gbias;
      float gate = 1.f / (1.f + __expf(-g));
      int row = r0 + 4 * q + r;
      gT[colN * 65 + row] = acc1[nf][r] * gate;
    }
  }
  __syncthreads();

  {
    int c = tid & 127, half = tid >> 7;
    int rbeg = half * 32, rend = rbeg + 32;
    int curs = -1; float run = 0.f;
    for (int r = rbeg; r < rend; ++r) {
      int s = rsrc[r];
      if (s != curs) {
        if (curs >= 0) atomAddF(&pool[(size_t)curs * 128 + c], run);
        curs = s; run = 0.f;
      }
      if (s >= 0) run += gT[c * 65 + r];
    }
    if (curs >= 0) atomAddF(&pool[(size_t)curs * 128 + c], run);
  }
}

// ---------------- finalize: out = LN(h + pool/max(cnt,1)) ----------------
__global__ __launch_bounds__(256) void finalize_kernel(
    const float* __restrict__ h, const float* __restrict__ pool,
    const int* __restrict__ degS, const float* __restrict__ g,
    const float* __restrict__ b, float* __restrict__ out)
{
  int t = blockIdx.x * 256 + threadIdx.x;
  int n = t >> 6, lane = t & 63;
  if (n >= N_NODES) return;
  float cnt = fmaxf((float)degS[n], 1.f);
  float a = h[(size_t)n * 128 + lane] + pool[(size_t)n * 128 + lane] / cnt;
  float c2 = h[(size_t)n * 128 + 64 + lane] + pool[(size_t)n * 128 + 64 + lane] / cnt;
  float s = a + c2, s2 = a * a + c2 * c2;
#pragma unroll
  for (int o = 1; o < 64; o <<= 1) { s += __shfl_xor(s, o); s2 += __shfl_xor(s2, o); }
  float mean = s * (1.f / 128.f);
  float var = s2 * (1.f / 128.f) - mean * mean;
  float rs = rsqrtf(var + 1e-5f);
  out[(size_t)n * 128 + lane] = (a - mean) * rs * g[lane] + b[lane];
  out[(size_t)n * 128 + 64 + lane] = (c2 - mean) * rs * g[64 + lane] + b[64 + lane];
}

// ---------------- host ----------------
extern "C" void kernel_launch(void* const* d_in, const int* in_sizes, int n_in,
                              void* d_out, int out_size, void* d_ws, size_t ws_size,
                              hipStream_t stream) {
  (void)in_sizes; (void)n_in; (void)out_size; (void)ws_size;
  const float* x     = (const float*)d_in[0];
  const int*   ei    = (const int*)d_in[1];
  const float* eattr = (const float*)d_in[2];
  const float* embW  = (const float*)d_in[3];
  const float* embB  = (const float*)d_in[4];
  const float* gWl   = (const float*)d_in[5];
  const float* gWr   = (const float*)d_in[6];
  const float* gWe   = (const float*)d_in[7];
  const float* gAtt  = (const float*)d_in[8];
  const float* gB    = (const float*)d_in[9];
  const float* lnG   = (const float*)d_in[10];
  const float* lnB   = (const float*)d_in[11];
  const float* spW1  = (const float*)d_in[12];
  const float* spB1  = (const float*)d_in[13];
  const float* spW2  = (const float*)d_in[14];
  const float* spB2  = (const float*)d_in[15];
  const float* spGW  = (const float*)d_in[16];
  const float* spGB  = (const float*)d_in[17];
  const float* fnG   = (const float*)d_in[18];
  const float* fnB   = (const float*)d_in[19];
  float* out = (float*)d_out;

  char* ws = (char*)d_ws;
  size_t off = 0;
  auto alloc = [&](size_t bytes) {
    void* p = ws + off;
    off = (off + bytes + 255) & ~(size_t)255;
    return p;
  };
  float* hA   = (float*)alloc((size_t)N_NODES * 128 * 4);
  float* hB   = (float*)alloc((size_t)N_NODES * 128 * 4);
  unsigned short* hbfA = (unsigned short*)alloc((size_t)N_NODES * 128 * 2);
  unsigned short* hbfB = (unsigned short*)alloc((size_t)N_NODES * 128 * 2);
  unsigned short* xlr  = (unsigned short*)alloc((size_t)N_NODES * 1024 * 2);
  unsigned short* sab  = (unsigned short*)alloc((size_t)N_NODES * 256 * 2);
  float* pool = (float*)alloc((size_t)N_NODES * 128 * 4);
  unsigned short* WlrT = (unsigned short*)alloc((size_t)4 * 1024 * 128 * 2);
  unsigned short* W1T  = (unsigned short*)alloc((size_t)256 * 128 * 2);
  unsigned short* W2T  = (unsigned short*)alloc((size_t)128 * 128 * 2);
  unsigned short* gWT  = (unsigned short*)alloc((size_t)128 * 128 * 2);
  int* degD = (int*)alloc((size_t)N_NODES * 4);
  int* degS = (int*)alloc((size_t)N_NODES * 4);
  int* offD = (int*)alloc((size_t)(N_NODES + 1) * 4);
  int* offS = (int*)alloc((size_t)(N_NODES + 1) * 4);
  int* curD = (int*)alloc((size_t)N_NODES * 4);
  int* curS = (int*)alloc((size_t)N_NODES * 4);
  int* eidD = (int*)alloc((size_t)N_EDGES * 4);
  int* eidS = (int*)alloc((size_t)N_EDGES * 4);
  int* esrc = (int*)alloc((size_t)N_EDGES * 4);
  float4* ea4 = (float4*)alloc((size_t)N_EDGES * 16);
  float* ea1 = (float*)alloc((size_t)N_EDGES * 4);

  hipMemsetAsync(degD, 0, (size_t)N_NODES * 4, stream);
  hipMemsetAsync(degS, 0, (size_t)N_NODES * 4, stream);
  hipMemsetAsync(pool, 0, (size_t)N_NODES * 128 * 4, stream);

  pack_kernel<<<(589824 + 255) / 256, 256, 0, stream>>>(gWl, gWr, spW1, spW2, spGW,
                                                        WlrT, W1T, W2T, gWT);
  embed_kernel<<<(N_NODES * 128) / 256, 256, 0, stream>>>(x, embW, embB, hA, hbfA);
  hist_kernel<<<(N_EDGES + 255) / 256, 256, 0, stream>>>(ei, degD, degS);
  scan_kernel<<<1, 1024, 0, stream>>>(degD, offD, curD, degS, offS, curS, N_NODES);
  scatter_kernel<<<(N_EDGES + 255) / 256, 256, 0, stream>>>(ei, curD, curS, eidD, eidS);
  reorder_kernel<<<(N_EDGES + 255) / 256, 256, 0, stream>>>(ei, eattr, eidD, esrc, ea4, ea1);

  const int MB64 = (N_NODES + 63) / 64;   // 157
  float* hcur = hA; float* hnext = hB;
  unsigned short* hbcur = hbfA; unsigned short* hbnext = hbfB;
  for (int l = 0; l < LAYERS; ++l) {
    mfma_gemm_kernel<<<dim3(16, MB64), 256, 0, stream>>>(
        hbcur, WlrT + (size_t)l * 1024 * 128, xlr, N_NODES, 1024);
    gat_agg_kernel<<<(N_NODES + 3) / 4, 256, 0, stream>>>(hcur, hnext, hbnext, xlr,
                                                          esrc, ea4, ea1, offD,
                                                          gWe + (size_t)l * EDIM * HC,
                                                          gAtt + (size_t)l * HC,
                                                          gB + (size_t)l * 128,
                                                          lnG + (size_t)l * 128,
                                                          lnB + (size_t)l * 128);
    float* t1 = hcur; hcur = hnext; hnext = t1;
    unsigned short* t2 = hbcur; hbcur = hbnext; hbnext = t2;
  }
  mfma_gemm_kernel<<<dim3(4, MB64), 256, 0, stream>>>(hbcur, W1T, sab, N_NODES, 256);
  sp_edge_kernel<<<(N_EDGES + 63) / 64, 256, 0, stream>>>(sab, spB1, W2T, spB2, gWT,
                                                          spGB, ei, eidS, pool);
  finalize_kernel<<<(N_NODES + 3) / 4, 256, 0, stream>>>(hcur, pool, degS, fnG, fnB, out);
}